// Round 8
// baseline (281.761 us; speedup 1.0000x reference)
//
#include <hip/hip_runtime.h>
#include <math.h>

#define D_MODEL 1024
#define NH 16
#define DK 64
#define S_LEN 1024
#define BATCH 4
#define MROWS (BATCH * S_LEN)  // 4096

typedef short bf16x8 __attribute__((ext_vector_type(8)));
typedef float f32x4 __attribute__((ext_vector_type(4)));
typedef unsigned short u16;

__device__ __forceinline__ float elu1(float x) {
    return x > 0.f ? x : (expf(x) - 1.f);
}

__device__ __forceinline__ u16 f2bf(float f) {
    union { float f; unsigned u; } v; v.f = f;
    unsigned u = v.u;
    return (u16)((u + 0x7fffu + ((u >> 16) & 1u)) >> 16);
}

// round-to-nearest (ties up) bf16 cast: 2 VALU ops instead of 4.
__device__ __forceinline__ u16 f2bf_fast(float f) {
    union { float f; unsigned u; } v; v.f = f;
    return (u16)((v.u + 0x8000u) >> 16);
}

__device__ __forceinline__ void async16(const void* g, void* l) {
    __builtin_amdgcn_global_load_lds(
        (const __attribute__((address_space(1))) unsigned int*)g,
        (__attribute__((address_space(3))) unsigned int*)l,
        16, 0, 0);
}

// ---------------------------------------------------------------------------
// cast_wt: W f32 [k][n] -> WT bf16 [n][k], for the 4 d_model x d_model weights.
__global__ __launch_bounds__(256) void cast_wt(
    const float* __restrict__ wq, const float* __restrict__ wk,
    const float* __restrict__ wv, const float* __restrict__ wo,
    u16* __restrict__ WT)
{
    __shared__ float T[64][65];
    const int z = blockIdx.z;
    const float* W = (z == 0) ? wq : ((z == 1) ? wk : ((z == 2) ? wv : wo));
    u16* O = WT + (size_t)z * D_MODEL * D_MODEL;
    const int tid = threadIdx.x;
    const int k0 = blockIdx.y * 64, n0 = blockIdx.x * 64;
    const int r = tid >> 4, c4 = (tid & 15) * 4;
    #pragma unroll
    for (int p = 0; p < 4; p++) {
        float4 v = *(const float4*)&W[(size_t)(k0 + r + p * 16) * D_MODEL + n0 + c4];
        T[r + p * 16][c4 + 0] = v.x; T[r + p * 16][c4 + 1] = v.y;
        T[r + p * 16][c4 + 2] = v.z; T[r + p * 16][c4 + 3] = v.w;
    }
    __syncthreads();
    #pragma unroll
    for (int p = 0; p < 4; p++) {
        const int i = r + p * 16;
        ushort4 o4;
        o4.x = f2bf(T[c4 + 0][i]); o4.y = f2bf(T[c4 + 1][i]);
        o4.z = f2bf(T[c4 + 2][i]); o4.w = f2bf(T[c4 + 3][i]);
        *(ushort4*)&O[(size_t)(n0 + i) * D_MODEL + k0 + c4] = o4;
    }
}

// ---------------------------------------------------------------------------
// cast_x: X f32 [MROWS][D] -> bf16, once per input tensor (q,k,v).
__global__ __launch_bounds__(256) void cast_x(
    const float* __restrict__ Xq, const float* __restrict__ Xk,
    const float* __restrict__ Xv, u16* __restrict__ Xb)
{
    const int z = blockIdx.y;
    const float* X = (z == 0) ? Xq : ((z == 1) ? Xk : Xv);
    u16* O = Xb + (size_t)z * MROWS * D_MODEL;
    const size_t i = ((size_t)blockIdx.x * 256 + threadIdx.x) * 8;
    float4 a = *(const float4*)&X[i];
    float4 b = *(const float4*)&X[i + 4];
    ushort4 o0, o1;
    o0.x = f2bf(a.x); o0.y = f2bf(a.y); o0.z = f2bf(a.z); o0.w = f2bf(a.w);
    o1.x = f2bf(b.x); o1.y = f2bf(b.y); o1.z = f2bf(b.z); o1.w = f2bf(b.w);
    *(ushort4*)&O[i] = o0;
    *(ushort4*)&O[i + 4] = o1;
}

// ---------------------------------------------------------------------------
// mask_pack v2: fully parallel. 8192 waves, 8 independent words per wave
// (loads batched for ILP, coalesced 256B per wave-iteration). ~5 us.
__global__ __launch_bounds__(256) void mask_pack(
    const int* __restrict__ mask, unsigned long long* __restrict__ Mb)
{
    const int gw = (blockIdx.x * 256 + threadIdx.x) >> 6;   // 0..8191
    const int lane = threadIdx.x & 63;
    int v[8];
    #pragma unroll
    for (int i = 0; i < 8; i++)
        v[i] = mask[((size_t)gw + (size_t)i * 8192) * 64 + lane];
    #pragma unroll
    for (int i = 0; i < 8; i++) {
        unsigned long long bits = __ballot(v[i] != 0);
        if (lane == 0) Mb[(size_t)gw + (size_t)i * 8192] = bits;
    }
}

// ---------------------------------------------------------------------------
// proj_fused v6: 128x64 tile, one head per block, BK=64 (was 32).
// Halves barrier count (16 K-steps): 16 MFMA + 12 ds_read + 6 async16 per
// wave between drains. LDS 33.8 KB still allows 4 blocks/CU (VGPR cap).
// Swizzle for 128B rows: src granule (l&7)^((l>>3)&7), read granule
// (ks*4+quad)^(col&7) -- bijective per 8-row stripe, conflict-free b128.
__global__ __launch_bounds__(256) void proj_fused(
    const u16* __restrict__ Xq, const u16* __restrict__ Xk, const u16* __restrict__ Xv,
    const u16* __restrict__ WTq, const u16* __restrict__ WTk, const u16* __restrict__ WTv,
    const float* __restrict__ bq, const float* __restrict__ bk, const float* __restrict__ bv,
    const float* __restrict__ spatial_w, const float* __restrict__ spatial_b,
    const float* __restrict__ qproj_w, const float* __restrict__ qproj_b,
    const float* __restrict__ kproj_w, const float* __restrict__ kproj_b,
    const float* __restrict__ vlin_w, const float* __restrict__ vlin_b,
    const float* __restrict__ chan_w, const float* __restrict__ chan_b,
    u16* __restrict__ Qh, u16* __restrict__ K2, u16* __restrict__ V2t,
    float* __restrict__ mB, float* __restrict__ uB, float* __restrict__ vB)
{
    // u16 units: As [128][64] = 0..8191 ; Bs [64][64] = 8192..12287 ;
    // W2t [64][72] = 12288..16895. Phase 2: Pchunk = smem + wave*1536
    // ([16][72], over dead As); Tb (V transpose) aliases W2t.
    __shared__ __align__(16) u16 smem[16896];
    __shared__ float auxA[64];
    __shared__ float auxS;

    u16* As = smem;
    u16* Bs = smem + 8192;
    u16* W2t = smem + 12288;

    const int z = blockIdx.z;
    const u16* X = (z == 0) ? Xq : ((z == 1) ? Xk : Xv);
    const u16* WT = (z == 0) ? WTq : ((z == 1) ? WTk : WTv);
    const float* B1 = (z == 0) ? bq : ((z == 1) ? bk : bv);
    const float* W2 = (z == 0) ? spatial_w : ((z == 1) ? kproj_w : vlin_w);
    const float* B2 = (z == 0) ? spatial_b : ((z == 1) ? kproj_b : vlin_b);

    const int tid = threadIdx.x;
    const int wave = tid >> 6, lane = tid & 63;
    const int col = lane & 15, quad = lane >> 4;
    const int r0 = blockIdx.x * 128;
    const int hh = blockIdx.y;          // head (one per block)
    const int n0 = hh * 64;

    // ---- stage W2t (transposed bf16) + aux ----
    #pragma unroll
    for (int p = 0; p < 4; p++) {
        int idx = p * 256 + tid;
        int f = idx >> 4, e4 = (idx & 15) * 4;
        float4 w4 = *(const float4*)&W2[f * 64 + e4];
        W2t[(e4 + 0) * 72 + f] = f2bf(w4.x);
        W2t[(e4 + 1) * 72 + f] = f2bf(w4.y);
        W2t[(e4 + 2) * 72 + f] = f2bf(w4.z);
        W2t[(e4 + 3) * 72 + f] = f2bf(w4.w);
    }
    if (z == 0) {
        {
            int row = tid >> 2, part = tid & 3;
            float s = 0.f;
            for (int e = part * 16; e < part * 16 + 16; e++) s += qproj_w[row * 64 + e];
            s += __shfl_xor(s, 1);
            s += __shfl_xor(s, 2);
            if (part == 0) auxA[row] = s * (1.f / 64.f);
        }
        if (tid < 64) {
            float s = qproj_b[tid];
            #pragma unroll
            for (int m = 1; m < 64; m <<= 1) s += __shfl_xor(s, m);
            if (tid == 0) auxS = s * (1.f / 64.f);
        }
    }

    // ---- phase 1: GEMM 128x64, BK=64, async16 staging + XOR swizzle ----
    const int srow8 = lane >> 3;                   // 0..7 (row within 8-row stripe)
    const int sg = ((lane & 7) ^ srow8) * 8;       // swizzled src granule (u16)

    const u16* ap = X + (size_t)(r0 + wave * 32 + srow8) * D_MODEL + sg;
    const u16* bp = WT + (size_t)(n0 + wave * 16 + srow8) * D_MODEL + sg;
    u16* adst = As + (wave * 32) * 64;
    u16* bdst = Bs + (wave * 16) * 64;

    f32x4 acc[2][4];
    #pragma unroll
    for (int i = 0; i < 2; i++)
        #pragma unroll
        for (int j = 0; j < 4; j++)
            acc[i][j] = (f32x4){0.f, 0.f, 0.f, 0.f};

    for (int k0 = 0; k0 < D_MODEL; k0 += 64) {
        if (k0) __syncthreads();
        #pragma unroll
        for (int i = 0; i < 4; i++)
            async16(ap + (size_t)(i * 8) * D_MODEL + k0, adst + i * 512);
        #pragma unroll
        for (int j = 0; j < 2; j++)
            async16(bp + (size_t)(j * 8) * D_MODEL + k0, bdst + j * 512);
        __syncthreads();
        #pragma unroll
        for (int ks = 0; ks < 2; ks++) {
            const int gk = ((ks * 4 + quad) ^ (col & 7)) * 8;  // swizzled read granule
            const u16* Abase = As + (wave * 32 + col) * 64 + gk;
            const u16* Bbase = Bs + col * 64 + gk;
            bf16x8 af[2], bfr[4];
            #pragma unroll
            for (int mi = 0; mi < 2; mi++) af[mi] = *(const bf16x8*)(Abase + mi * 1024);
            #pragma unroll
            for (int ni = 0; ni < 4; ni++) bfr[ni] = *(const bf16x8*)(Bbase + ni * 1024);
            #pragma unroll
            for (int mi = 0; mi < 2; mi++)
                #pragma unroll
                for (int ni = 0; ni < 4; ni++)
                    acc[mi][ni] = __builtin_amdgcn_mfma_f32_16x16x32_bf16(af[mi], bfr[ni], acc[mi][ni], 0, 0, 0);
        }
    }

    // ---- phase 2: epilogue ----
    float b1v[4];
    #pragma unroll
    for (int ni = 0; ni < 4; ni++) b1v[ni] = B1[n0 + ni * 16 + col];

    const int rbase = r0 + wave * 32;
    const int b = r0 >> 10;
    const int s0 = (r0 & 1023) + wave * 32;
    const size_t svecbase = ((size_t)b * NH + hh) * S_LEN;

    if (z == 1) {
        float cw[4], cb[4];
        #pragma unroll
        for (int ni = 0; ni < 4; ni++) { cw[ni] = chan_w[ni * 16 + col]; cb[ni] = chan_b[ni * 16 + col]; }
        #pragma unroll
        for (int mi = 0; mi < 2; mi++)
            #pragma unroll
            for (int r = 0; r < 4; r++) {
                float su = 0.f, sv = 0.f;
                #pragma unroll
                for (int ni = 0; ni < 4; ni++) {
                    float p = acc[mi][ni][r] + b1v[ni];
                    su += p * cw[ni];
                    sv += p * cb[ni];
                }
                su += __shfl_xor(su, 1); su += __shfl_xor(su, 2);
                su += __shfl_xor(su, 4); su += __shfl_xor(su, 8);
                sv += __shfl_xor(sv, 1); sv += __shfl_xor(sv, 2);
                sv += __shfl_xor(sv, 4); sv += __shfl_xor(sv, 8);
                if (col == 0) {
                    const size_t idx = svecbase + s0 + mi * 16 + quad * 4 + r;
                    uB[idx] = su;
                    vB[idx] = sv;
                }
            }
    }

    __syncthreads();  // phase-1 As/Bs reads done; safe to alias Pchunk

    u16* Pchunk = smem + wave * 1536;
    bf16x8 bf2r[4][2];
    #pragma unroll
    for (int ni = 0; ni < 4; ni++) {
        bf2r[ni][0] = *(const bf16x8*)&W2t[(ni * 16 + col) * 72 + quad * 8];
        bf2r[ni][1] = *(const bf16x8*)&W2t[(ni * 16 + col) * 72 + 32 + quad * 8];
    }
    float qs[2][4][4];
    #pragma unroll
    for (int mi = 0; mi < 2; mi++) {
        #pragma unroll
        for (int ni = 0; ni < 4; ni++)
            #pragma unroll
            for (int r = 0; r < 4; r++)
                Pchunk[(quad * 4 + r) * 72 + ni * 16 + col] = f2bf(acc[mi][ni][r] + b1v[ni]);
        __builtin_amdgcn_s_waitcnt(0xc07f);  // lgkmcnt(0): wave-local chunk visible
        __builtin_amdgcn_sched_barrier(0);
        bf16x8 a0 = *(const bf16x8*)&Pchunk[col * 72 + quad * 8];
        bf16x8 a1 = *(const bf16x8*)&Pchunk[col * 72 + 32 + quad * 8];
        __builtin_amdgcn_s_waitcnt(0xc07f);  // reads done before mi+1 overwrites
        __builtin_amdgcn_sched_barrier(0);
        #pragma unroll
        for (int ni = 0; ni < 4; ni++) {
            f32x4 c = (f32x4){0.f, 0.f, 0.f, 0.f};
            c = __builtin_amdgcn_mfma_f32_16x16x32_bf16(a0, bf2r[ni][0], c, 0, 0, 0);
            c = __builtin_amdgcn_mfma_f32_16x16x32_bf16(a1, bf2r[ni][1], c, 0, 0, 0);
            const float bb = B2[ni * 16 + col];
            #pragma unroll
            for (int r = 0; r < 4; r++) qs[mi][ni][r] = elu1(c[r] + bb);
        }
    }

    if (z == 0) {
        float aw[4];
        #pragma unroll
        for (int ni = 0; ni < 4; ni++) aw[ni] = auxA[ni * 16 + col];
        #pragma unroll
        for (int mi = 0; mi < 2; mi++)
            #pragma unroll
            for (int r = 0; r < 4; r++) {
                float pm = 0.f;
                #pragma unroll
                for (int ni = 0; ni < 4; ni++) pm += qs[mi][ni][r] * aw[ni];
                pm += __shfl_xor(pm, 1); pm += __shfl_xor(pm, 2);
                pm += __shfl_xor(pm, 4); pm += __shfl_xor(pm, 8);
                if (col == 0)
                    mB[svecbase + s0 + mi * 16 + quad * 4 + r] = pm + auxS;
            }
        #pragma unroll
        for (int mi = 0; mi < 2; mi++)
            #pragma unroll
            for (int ni = 0; ni < 4; ni++)
                #pragma unroll
                for (int r = 0; r < 4; r++)
                    Qh[(size_t)(rbase + mi * 16 + quad * 4 + r) * D_MODEL
                       + n0 + ni * 16 + col] = f2bf(qs[mi][ni][r] * 0.125f);
    } else if (z == 1) {
        #pragma unroll
        for (int mi = 0; mi < 2; mi++)
            #pragma unroll
            for (int ni = 0; ni < 4; ni++)
                #pragma unroll
                for (int r = 0; r < 4; r++)
                    K2[(size_t)(rbase + mi * 16 + quad * 4 + r) * D_MODEL
                       + n0 + ni * 16 + col] = f2bf(qs[mi][ni][r]);
    } else {
        u16* Tb = W2t;
        __syncthreads();
        #pragma unroll
        for (int p = 0; p < 2; p++) {
            if ((wave >> 1) == p) {
                const int sloc = (wave & 1) * 32;
                #pragma unroll
                for (int mi = 0; mi < 2; mi++)
                    #pragma unroll
                    for (int ni = 0; ni < 4; ni++)
                        #pragma unroll
                        for (int r = 0; r < 4; r++)
                            Tb[(ni * 16 + col) * 72 + sloc + mi * 16 + quad * 4 + r] =
                                f2bf(qs[mi][ni][r]);
            }
            __syncthreads();
            {
                const int d = tid >> 2, seg = tid & 3;
                u16* dst = V2t + (((size_t)b * NH + hh) * DK + d) * S_LEN
                         + (r0 & 1023) + p * 64 + seg * 16;
                *(uint4*)dst = *(const uint4*)&Tb[d * 72 + seg * 16];
                *(uint4*)(dst + 8) = *(const uint4*)&Tb[d * 72 + seg * 16 + 8];
            }
            if (p == 0) __syncthreads();
        }
    }
}

// ---------------------------------------------------------------------------
// MFMA flash attention v3: single-buffered K2s/V2s (two barriers/tile) ->
// LDS 27.6 KB -> ~5 blocks/CU. Fast sigmoid via v_rcp, fast bf16 rounding,
// bitmask mask, direct register reload, setprio around MFMA clusters,
// XCD-aware block swizzle (8 (b,h) groups = 2 MB K/V per XCD L2).
__global__ __launch_bounds__(256) void attn_mfma(
    const u16* __restrict__ Qh, const u16* __restrict__ K2h, const u16* __restrict__ V2t,
    const float* __restrict__ Mq, const float* __restrict__ Uk, const float* __restrict__ Vk,
    const unsigned long long* __restrict__ Mb, u16* __restrict__ X)
{
    __shared__ u16 K2s[64][72];
    __shared__ u16 V2s[64][72];
    __shared__ u16 Ps[4][16][72];

    const int tid = threadIdx.x;
    const int wave = tid >> 6, lane = tid & 63;
    const int col = lane & 15, quad = lane >> 4;

    // XCD swizzle: f%8 -> XCD; give each XCD 8 consecutive (b,h) groups.
    const int f = blockIdx.x;
    const int o = (f & 7) * 128 + (f >> 3);
    const int q0 = (o & 15) * 64;
    const int h = (o >> 4) & 15;
    const int b = o >> 8;

    const size_t hb = ((size_t)(b * NH + h)) * S_LEN * DK;
    const size_t sb = ((size_t)(b * NH + h)) * S_LEN;

    bf16x8 qf0, qf1;
    {
        const u16* qp = Qh + (size_t)(b * S_LEN + q0 + wave * 16 + col) * D_MODEL + h * 64 + quad * 8;
        qf0 = *(const bf16x8*)qp;
        qf1 = *(const bf16x8*)(qp + 32);
    }
    float mqv[4];
    #pragma unroll
    for (int r = 0; r < 4; r++)
        mqv[r] = Mq[sb + q0 + wave * 16 + quad * 4 + r];

    const int srow = tid >> 2, sseg = tid & 3;
    const u16* ksrc = K2h + (size_t)(b * S_LEN + srow) * D_MODEL + h * 64 + sseg * 16;
    const u16* vsrc = V2t + hb + (size_t)srow * S_LEN + sseg * 16;
    const unsigned long long* mbase = Mb
        + ((size_t)b * S_LEN + q0 + wave * 16 + quad * 4) * (S_LEN / 64);
    const unsigned msel0 = 1u << col, msel1 = msel0 << 16;

    // tile-0 prefetch
    uint4 ka = *(const uint4*)(ksrc);
    uint4 kb = *(const uint4*)(ksrc + 8);
    uint4 va = *(const uint4*)(vsrc);
    uint4 vb = *(const uint4*)(vsrc + 8);
    float ku[4], kv[4];
    unsigned long long wm[4];
    #pragma unroll
    for (int nb = 0; nb < 4; nb++) {
        ku[nb] = Uk[sb + nb * 16 + col];
        kv[nb] = Vk[sb + nb * 16 + col];
    }
    #pragma unroll
    for (int r = 0; r < 4; r++) wm[r] = mbase[r * 16];

    float psum[4] = {0.f, 0.f, 0.f, 0.f};
    f32x4 o4[4];
    #pragma unroll
    for (int nb = 0; nb < 4; nb++) o4[nb] = (f32x4){0.f, 0.f, 0.f, 0.f};

    for (int t = 0; t < 16; t++) {
        // stores of tile t (prev iter's barrier B guarantees reads of t-1 done)
        *(uint4*)&K2s[srow][sseg * 16]     = ka;
        *(uint4*)&K2s[srow][sseg * 16 + 8] = kb;
        *(uint4*)&V2s[srow][sseg * 16]     = va;
        *(uint4*)&V2s[srow][sseg * 16 + 8] = vb;
        __syncthreads();  // barrier A: stores visible

        if (t < 15) {   // reload K/V regs for t+1 (latency hidden under QKT+PV)
            const int k1 = (t + 1) * 64;
            const u16* ks = ksrc + (size_t)k1 * D_MODEL;
            const u16* vs = vsrc + k1;
            ka = *(const uint4*)(ks);
            kb = *(const uint4*)(ks + 8);
            va = *(const uint4*)(vs);
            vb = *(const uint4*)(vs + 8);
        }

        // ---- QK^T (Q pre-scaled by 1/8) ----
        __builtin_amdgcn_s_setprio(1);
        f32x4 sc[4];
        #pragma unroll
        for (int nb = 0; nb < 4; nb++) {
            bf16x8 b0 = *(const bf16x8*)&K2s[nb * 16 + col][quad * 8];
            bf16x8 b1 = *(const bf16x8*)&K2s[nb * 16 + col][32 + quad * 8];
            f32x4 c = (f32x4){0.f, 0.f, 0.f, 0.f};
            c = __builtin_amdgcn_mfma_f32_16x16x32_bf16(qf0, b0, c, 0, 0, 0);
            c = __builtin_amdgcn_mfma_f32_16x16x32_bf16(qf1, b1, c, 0, 0, 0);
            sc[nb] = c;
        }
        __builtin_amdgcn_s_setprio(0);

        // ---- gate, mask (bit test), exp (fixed max 0) ----
        #pragma unroll
        for (int nb = 0; nb < 4; nb++) {
            #pragma unroll
            for (int r = 0; r < 4; r++) {
                float e = __expf(-(mqv[r] * ku[nb] + kv[nb]));
                float g = __builtin_amdgcn_rcpf(1.f + e);
                float sv = sc[nb][r] * g;
                const unsigned bits = (nb < 2) ? (unsigned)wm[r]
                                               : (unsigned)(wm[r] >> 32);
                sv = (bits & ((nb & 1) ? msel1 : msel0)) ? sv : -30.f;
                float p = __expf(sv);
                psum[r] += p;
                Ps[wave][quad * 4 + r][nb * 16 + col] = f2bf_fast(p);
            }
        }
        if (t < 15) {   // reload gate/mask regs for t+1 (dead after gate loop)
            const int k1 = (t + 1) * 64;
            #pragma unroll
            for (int nb = 0; nb < 4; nb++) {
                ku[nb] = Uk[sb + k1 + nb * 16 + col];
                kv[nb] = Vk[sb + k1 + nb * 16 + col];
            }
            #pragma unroll
            for (int r = 0; r < 4; r++) wm[r] = mbase[r * 16 + t + 1];
        }
        __builtin_amdgcn_s_waitcnt(0xc07f);  // lgkmcnt(0); vm prefetch in flight
        __builtin_amdgcn_sched_barrier(0);
        bf16x8 a0 = *(const bf16x8*)&Ps[wave][col][quad * 8];
        bf16x8 a1 = *(const bf16x8*)&Ps[wave][col][32 + quad * 8];

        // ---- PV ----
        __builtin_amdgcn_s_setprio(1);
        #pragma unroll
        for (int nb = 0; nb < 4; nb++) {
            bf16x8 b0 = *(const bf16x8*)&V2s[nb * 16 + col][quad * 8];
            bf16x8 b1 = *(const bf16x8*)&V2s[nb * 16 + col][32 + quad * 8];
            o4[nb] = __builtin_amdgcn_mfma_f32_16x16x32_bf16(a0, b0, o4[nb], 0, 0, 0);
            o4[nb] = __builtin_amdgcn_mfma_f32_16x16x32_bf16(a1, b1, o4[nb], 0, 0, 0);
        }
        __builtin_amdgcn_s_setprio(0);
        __syncthreads();  // barrier B: all reads done; next stores safe
    }

    #pragma unroll
    for (int r = 0; r < 4; r++) {
        float t = psum[r];
        t += __shfl_xor(t, 1);
        t += __shfl_xor(t, 2);
        t += __shfl_xor(t, 4);
        t += __shfl_xor(t, 8);
        float inv = __builtin_amdgcn_rcpf(t);
        u16* xp = X + (size_t)(b * S_LEN + q0 + wave * 16 + quad * 4 + r) * D_MODEL + h * 64 + col;
        #pragma unroll
        for (int nb = 0; nb < 4; nb++)
            xp[nb * 16] = f2bf_fast(o4[nb][r] * inv);
    }
}

// ---------------------------------------------------------------------------
// out_gemm v2: C(f32) = A(bf16) @ WT^T + bias. 128x64 tiles, grid (32,16)
// = 512 blocks (2/CU). Per wave: 32 rows x 64 cols, acc[2][4], 8 MFMA and
// 6 ds_read_b128 per K-step. Same XOR swizzle as proj_fused v4.
__global__ __launch_bounds__(256) void out_gemm(
    const u16* __restrict__ A, const u16* __restrict__ WT,
    const float* __restrict__ bias, float* __restrict__ C)
{
    __shared__ u16 As[128 * 32];
    __shared__ u16 Bs[64 * 32];

    const int tid = threadIdx.x;
    const int wave = tid >> 6, lane = tid & 63;
    const int col = lane & 15, quad = lane >> 4;
    const int r0 = blockIdx.x * 128, n0 = blockIdx.y * 64;

    const int srow = lane >> 2;
    const int sg = ((lane & 3) ^ ((lane >> 3) & 3)) * 8;
    const u16* ap = A + (size_t)(r0 + wave * 32 + srow) * D_MODEL + sg;
    const u16* bp = WT + (size_t)(n0 + wave * 16 + srow) * D_MODEL + sg;
    u16* adst0 = As + (wave * 32) * 32;  u16* adst1 = adst0 + 512;
    u16* bdst = Bs + wave * 16 * 32;

    f32x4 acc[2][4];
    #pragma unroll
    for (int i = 0; i < 2; i++)
        #pragma unroll
        for (int j = 0; j < 4; j++)
            acc[i][j] = (f32x4){0.f, 0.f, 0.f, 0.f};

    const int gsw = (quad ^ ((col >> 1) & 3)) * 8;

    for (int k0 = 0; k0 < D_MODEL; k0 += 32) {
        if (k0) __syncthreads();
        async16(ap + k0, adst0);
        async16(ap + (size_t)16 * D_MODEL + k0, adst1);
        async16(bp + k0, bdst);
        __syncthreads();
        const u16* Ab = As + (wave * 32 + col) * 32 + gsw;
        const u16* Bb = Bs + col * 32 + gsw;
        bf16x8 af[2], bfr[4];
        #pragma unroll
        for (int mi = 0; mi < 2; mi++) af[mi] = *(const bf16x8*)(Ab + mi * 512);
        #pragma unroll
        for (int ni = 0; ni < 4; ni++) bfr[ni] = *(const bf16x8*)(Bb + ni * 512);
        #pragma unroll
        for (int mi = 0; mi < 2; mi++)
            #pragma unroll
            for (int ni = 0; ni < 4; ni++)
                acc[mi][ni] = __builtin_amdgcn_mfma_f32_16x16x32_bf16(af[mi], bfr[ni], acc[mi][ni], 0, 0, 0);
    }

    #pragma unroll
    for (int mi = 0; mi < 2; mi++)
        #pragma unroll
        for (int ni = 0; ni < 4; ni++) {
            const int gr = r0 + wave * 32 + mi * 16 + quad * 4;
            const int gc = n0 + ni * 16 + col;
            const float bb = bias[gc];
            #pragma unroll
            for (int r = 0; r < 4; r++)
                C[(size_t)(gr + r) * D_MODEL + gc] = acc[mi][ni][r] + bb;
        }
}

// ---------------------------------------------------------------------------
extern "C" void kernel_launch(void* const* d_in, const int* in_sizes, int n_in,
                              void* d_out, int out_size, void* d_ws, size_t ws_size,
                              hipStream_t stream) {
    (void)in_sizes; (void)n_in; (void)out_size; (void)ws_size;
    const float* query = (const float*)d_in[0];
    const float* key_  = (const float*)d_in[1];
    const float* value = (const float*)d_in[2];
    const int*   mask  = (const int*)d_in[3];
    const float* wq = (const float*)d_in[4];  const float* bq = (const float*)d_in[5];
    const float* wk = (const float*)d_in[6];  const float* bk = (const float*)d_in[7];
    const float* wv = (const float*)d_in[8];  const float* bv = (const float*)d_in[9];
    const float* wo = (const float*)d_in[10]; const float* bo = (const float*)d_in[11];
    const float* spatial_w = (const float*)d_in[12]; const float* spatial_b = (const float*)d_in[13];
    const float* qproj_w   = (const float*)d_in[14]; const float* qproj_b   = (const float*)d_in[15];
    const float* kproj_w   = (const float*)d_in[16]; const float* kproj_b   = (const float*)d_in[17];
    const float* vlin_w    = (const float*)d_in[18]; const float* vlin_b    = (const float*)d_in[19];
    const float* chan_w    = (const float*)d_in[20]; const float* chan_b    = (const float*)d_in[21];
    float* out = (float*)d_out;

    char* ws = (char*)d_ws;
    u16* Qh  = (u16*)ws;                          // 8 MB [B,S,H,DK] bf16 (pre-scaled 1/8)
    u16* K2  = (u16*)(ws + ((size_t)8  << 20));   // 8 MB [B,S,H,DK] bf16
    u16* Xb  = (u16*)(ws + ((size_t)16 << 20));   // 8 MB [B,S,D] bf16 (attn out)
    u16* WT  = (u16*)(ws + ((size_t)24 << 20));   // 8 MB: 4 transposed weights
    u16* V2t = (u16*)(ws + ((size_t)32 << 20));   // 8 MB [B,H,DK,S] bf16
    float* mB = (float*)(ws + ((size_t)40 << 20));
    float* uB = mB + (size_t)BATCH * NH * S_LEN;
    float* vB = uB + (size_t)BATCH * NH * S_LEN;
    unsigned long long* Mbits = (unsigned long long*)(ws + ((size_t)41 << 20)); // 512 KB
    u16* Xbf = (u16*)(ws + ((size_t)42 << 20));   // 24 MB: 3x [B,S,D] bf16 inputs
    const size_t WSZ = (size_t)D_MODEL * D_MODEL;
    const size_t XSZ = (size_t)MROWS * D_MODEL;

    cast_wt<<<dim3(16, 16, 4), 256, 0, stream>>>(wq, wk, wv, wo, WT);
    cast_x<<<dim3(MROWS * D_MODEL / 2048, 3), 256, 0, stream>>>(query, key_, value, Xbf);
    mask_pack<<<dim3(2048), 256, 0, stream>>>(mask, Mbits);
    proj_fused<<<dim3(32, 16, 3), 256, 0, stream>>>(Xbf, Xbf + XSZ, Xbf + 2 * XSZ,
        WT, WT + WSZ, WT + 2 * WSZ, bq, bk, bv,
        spatial_w, spatial_b, qproj_w, qproj_b, kproj_w, kproj_b,
        vlin_w, vlin_b, chan_w, chan_b,
        Qh, K2, V2t, mB, uB, vB);
    attn_mfma<<<dim3(1024), 256, 0, stream>>>(Qh, K2, V2t, mB, uB, vB, Mbits, Xb);
    out_gemm<<<dim3(32, 16), 256, 0, stream>>>(Xb, WT + 3 * WSZ, bo, out);
}

// Round 9
// 276.999 us; speedup vs baseline: 1.0172x; 1.0172x over previous
//
#include <hip/hip_runtime.h>
#include <math.h>

#define D_MODEL 1024
#define NH 16
#define DK 64
#define S_LEN 1024
#define BATCH 4
#define MROWS (BATCH * S_LEN)  // 4096

typedef short bf16x8 __attribute__((ext_vector_type(8)));
typedef float f32x4 __attribute__((ext_vector_type(4)));
typedef unsigned short u16;

__device__ __forceinline__ float elu1(float x) {
    return x > 0.f ? x : (expf(x) - 1.f);
}

__device__ __forceinline__ u16 f2bf(float f) {
    union { float f; unsigned u; } v; v.f = f;
    unsigned u = v.u;
    return (u16)((u + 0x7fffu + ((u >> 16) & 1u)) >> 16);
}

// round-to-nearest (ties up) bf16 cast: 2 VALU ops instead of 4.
__device__ __forceinline__ u16 f2bf_fast(float f) {
    union { float f; unsigned u; } v; v.f = f;
    return (u16)((v.u + 0x8000u) >> 16);
}

__device__ __forceinline__ void async16(const void* g, void* l) {
    __builtin_amdgcn_global_load_lds(
        (const __attribute__((address_space(1))) unsigned int*)g,
        (__attribute__((address_space(3))) unsigned int*)l,
        16, 0, 0);
}

// ---------------------------------------------------------------------------
// prep: fused cast_wt + cast_x + mask_pack (all independent, all memory-bound)
// in ONE dispatch. Blocks 0..1023: weight transpose-cast; 1024..7167: X cast;
// 7168..9215: mask bitpack. Branches are block-uniform.
__global__ __launch_bounds__(256) void prep(
    const float* __restrict__ wq, const float* __restrict__ wk,
    const float* __restrict__ wv, const float* __restrict__ wo,
    u16* __restrict__ WT,
    const float* __restrict__ Xq, const float* __restrict__ Xk,
    const float* __restrict__ Xv, u16* __restrict__ Xb,
    const int* __restrict__ mask, unsigned long long* __restrict__ Mb)
{
    __shared__ float T[64][65];
    const int bid = blockIdx.x;
    const int tid = threadIdx.x;

    if (bid < 1024) {
        // ---- cast_wt: W f32 [k][n] -> WT bf16 [n][k] ----
        const int z = bid >> 8;
        const int rem = bid & 255;
        const int n0 = (rem & 15) * 64, k0 = (rem >> 4) * 64;
        const float* W = (z == 0) ? wq : ((z == 1) ? wk : ((z == 2) ? wv : wo));
        u16* O = WT + (size_t)z * D_MODEL * D_MODEL;
        const int r = tid >> 4, c4 = (tid & 15) * 4;
        #pragma unroll
        for (int p = 0; p < 4; p++) {
            float4 v = *(const float4*)&W[(size_t)(k0 + r + p * 16) * D_MODEL + n0 + c4];
            T[r + p * 16][c4 + 0] = v.x; T[r + p * 16][c4 + 1] = v.y;
            T[r + p * 16][c4 + 2] = v.z; T[r + p * 16][c4 + 3] = v.w;
        }
        __syncthreads();
        #pragma unroll
        for (int p = 0; p < 4; p++) {
            const int i = r + p * 16;
            ushort4 o4;
            o4.x = f2bf(T[c4 + 0][i]); o4.y = f2bf(T[c4 + 1][i]);
            o4.z = f2bf(T[c4 + 2][i]); o4.w = f2bf(T[c4 + 3][i]);
            *(ushort4*)&O[(size_t)(n0 + i) * D_MODEL + k0 + c4] = o4;
        }
    } else if (bid < 1024 + 6144) {
        // ---- cast_x: X f32 -> bf16 ----
        const int idx = bid - 1024;
        const int z = idx >> 11;            // 0..2
        const int bx = idx & 2047;
        const float* X = (z == 0) ? Xq : ((z == 1) ? Xk : Xv);
        u16* O = Xb + (size_t)z * MROWS * D_MODEL;
        const size_t i = ((size_t)bx * 256 + tid) * 8;
        float4 a = *(const float4*)&X[i];
        float4 b = *(const float4*)&X[i + 4];
        ushort4 o0, o1;
        o0.x = f2bf(a.x); o0.y = f2bf(a.y); o0.z = f2bf(a.z); o0.w = f2bf(a.w);
        o1.x = f2bf(b.x); o1.y = f2bf(b.y); o1.z = f2bf(b.z); o1.w = f2bf(b.w);
        *(ushort4*)&O[i] = o0;
        *(ushort4*)&O[i + 4] = o1;
    } else {
        // ---- mask_pack: int32 [B][S][S] -> u64 bitmask via ballot ----
        const int bx = bid - 7168;
        const int gw = (bx * 256 + tid) >> 6;   // 0..8191
        const int lane = tid & 63;
        int v[8];
        #pragma unroll
        for (int i = 0; i < 8; i++)
            v[i] = mask[((size_t)gw + (size_t)i * 8192) * 64 + lane];
        #pragma unroll
        for (int i = 0; i < 8; i++) {
            unsigned long long bits = __ballot(v[i] != 0);
            if (lane == 0) Mb[(size_t)gw + (size_t)i * 8192] = bits;
        }
    }
}

// ---------------------------------------------------------------------------
// proj_fused v6: 128x64 tile, one head per block, BK=64.
// 16 K-steps: 16 MFMA + 12 ds_read + 6 async16 per wave between drains.
// Swizzle for 128B rows: src granule (l&7)^((l>>3)&7), read granule
// (ks*4+quad)^(col&7) -- bijective per 8-row stripe, conflict-free b128.
__global__ __launch_bounds__(256) void proj_fused(
    const u16* __restrict__ Xq, const u16* __restrict__ Xk, const u16* __restrict__ Xv,
    const u16* __restrict__ WTq, const u16* __restrict__ WTk, const u16* __restrict__ WTv,
    const float* __restrict__ bq, const float* __restrict__ bk, const float* __restrict__ bv,
    const float* __restrict__ spatial_w, const float* __restrict__ spatial_b,
    const float* __restrict__ qproj_w, const float* __restrict__ qproj_b,
    const float* __restrict__ kproj_w, const float* __restrict__ kproj_b,
    const float* __restrict__ vlin_w, const float* __restrict__ vlin_b,
    const float* __restrict__ chan_w, const float* __restrict__ chan_b,
    u16* __restrict__ Qh, u16* __restrict__ K2, u16* __restrict__ V2t,
    float* __restrict__ mB, float* __restrict__ uB, float* __restrict__ vB)
{
    __shared__ __align__(16) u16 smem[16896];
    __shared__ float auxA[64];
    __shared__ float auxS;

    u16* As = smem;
    u16* Bs = smem + 8192;
    u16* W2t = smem + 12288;

    const int z = blockIdx.z;
    const u16* X = (z == 0) ? Xq : ((z == 1) ? Xk : Xv);
    const u16* WT = (z == 0) ? WTq : ((z == 1) ? WTk : WTv);
    const float* B1 = (z == 0) ? bq : ((z == 1) ? bk : bv);
    const float* W2 = (z == 0) ? spatial_w : ((z == 1) ? kproj_w : vlin_w);
    const float* B2 = (z == 0) ? spatial_b : ((z == 1) ? kproj_b : vlin_b);

    const int tid = threadIdx.x;
    const int wave = tid >> 6, lane = tid & 63;
    const int col = lane & 15, quad = lane >> 4;
    const int r0 = blockIdx.x * 128;
    const int hh = blockIdx.y;          // head (one per block)
    const int n0 = hh * 64;

    // ---- stage W2t (transposed bf16) + aux ----
    #pragma unroll
    for (int p = 0; p < 4; p++) {
        int idx = p * 256 + tid;
        int f = idx >> 4, e4 = (idx & 15) * 4;
        float4 w4 = *(const float4*)&W2[f * 64 + e4];
        W2t[(e4 + 0) * 72 + f] = f2bf(w4.x);
        W2t[(e4 + 1) * 72 + f] = f2bf(w4.y);
        W2t[(e4 + 2) * 72 + f] = f2bf(w4.z);
        W2t[(e4 + 3) * 72 + f] = f2bf(w4.w);
    }
    if (z == 0) {
        {
            int row = tid >> 2, part = tid & 3;
            float s = 0.f;
            for (int e = part * 16; e < part * 16 + 16; e++) s += qproj_w[row * 64 + e];
            s += __shfl_xor(s, 1);
            s += __shfl_xor(s, 2);
            if (part == 0) auxA[row] = s * (1.f / 64.f);
        }
        if (tid < 64) {
            float s = qproj_b[tid];
            #pragma unroll
            for (int m = 1; m < 64; m <<= 1) s += __shfl_xor(s, m);
            if (tid == 0) auxS = s * (1.f / 64.f);
        }
    }

    // ---- phase 1: GEMM 128x64, BK=64, async16 staging + XOR swizzle ----
    const int srow8 = lane >> 3;                   // 0..7
    const int sg = ((lane & 7) ^ srow8) * 8;       // swizzled src granule (u16)

    const u16* ap = X + (size_t)(r0 + wave * 32 + srow8) * D_MODEL + sg;
    const u16* bp = WT + (size_t)(n0 + wave * 16 + srow8) * D_MODEL + sg;
    u16* adst = As + (wave * 32) * 64;
    u16* bdst = Bs + (wave * 16) * 64;

    f32x4 acc[2][4];
    #pragma unroll
    for (int i = 0; i < 2; i++)
        #pragma unroll
        for (int j = 0; j < 4; j++)
            acc[i][j] = (f32x4){0.f, 0.f, 0.f, 0.f};

    for (int k0 = 0; k0 < D_MODEL; k0 += 64) {
        if (k0) __syncthreads();
        #pragma unroll
        for (int i = 0; i < 4; i++)
            async16(ap + (size_t)(i * 8) * D_MODEL + k0, adst + i * 512);
        #pragma unroll
        for (int j = 0; j < 2; j++)
            async16(bp + (size_t)(j * 8) * D_MODEL + k0, bdst + j * 512);
        __syncthreads();
        #pragma unroll
        for (int ks = 0; ks < 2; ks++) {
            const int gk = ((ks * 4 + quad) ^ (col & 7)) * 8;
            const u16* Abase = As + (wave * 32 + col) * 64 + gk;
            const u16* Bbase = Bs + col * 64 + gk;
            bf16x8 af[2], bfr[4];
            #pragma unroll
            for (int mi = 0; mi < 2; mi++) af[mi] = *(const bf16x8*)(Abase + mi * 1024);
            #pragma unroll
            for (int ni = 0; ni < 4; ni++) bfr[ni] = *(const bf16x8*)(Bbase + ni * 1024);
            #pragma unroll
            for (int mi = 0; mi < 2; mi++)
                #pragma unroll
                for (int ni = 0; ni < 4; ni++)
                    acc[mi][ni] = __builtin_amdgcn_mfma_f32_16x16x32_bf16(af[mi], bfr[ni], acc[mi][ni], 0, 0, 0);
        }
    }

    // ---- phase 2: epilogue ----
    float b1v[4];
    #pragma unroll
    for (int ni = 0; ni < 4; ni++) b1v[ni] = B1[n0 + ni * 16 + col];

    const int rbase = r0 + wave * 32;
    const int b = r0 >> 10;
    const int s0 = (r0 & 1023) + wave * 32;
    const size_t svecbase = ((size_t)b * NH + hh) * S_LEN;

    if (z == 1) {
        float cw[4], cb[4];
        #pragma unroll
        for (int ni = 0; ni < 4; ni++) { cw[ni] = chan_w[ni * 16 + col]; cb[ni] = chan_b[ni * 16 + col]; }
        #pragma unroll
        for (int mi = 0; mi < 2; mi++)
            #pragma unroll
            for (int r = 0; r < 4; r++) {
                float su = 0.f, sv = 0.f;
                #pragma unroll
                for (int ni = 0; ni < 4; ni++) {
                    float p = acc[mi][ni][r] + b1v[ni];
                    su += p * cw[ni];
                    sv += p * cb[ni];
                }
                su += __shfl_xor(su, 1); su += __shfl_xor(su, 2);
                su += __shfl_xor(su, 4); su += __shfl_xor(su, 8);
                sv += __shfl_xor(sv, 1); sv += __shfl_xor(sv, 2);
                sv += __shfl_xor(sv, 4); sv += __shfl_xor(sv, 8);
                if (col == 0) {
                    const size_t idx = svecbase + s0 + mi * 16 + quad * 4 + r;
                    uB[idx] = su;
                    vB[idx] = sv;
                }
            }
    }

    __syncthreads();  // phase-1 As/Bs reads done; safe to alias Pchunk

    u16* Pchunk = smem + wave * 1536;
    bf16x8 bf2r[4][2];
    #pragma unroll
    for (int ni = 0; ni < 4; ni++) {
        bf2r[ni][0] = *(const bf16x8*)&W2t[(ni * 16 + col) * 72 + quad * 8];
        bf2r[ni][1] = *(const bf16x8*)&W2t[(ni * 16 + col) * 72 + 32 + quad * 8];
    }
    float qs[2][4][4];
    #pragma unroll
    for (int mi = 0; mi < 2; mi++) {
        #pragma unroll
        for (int ni = 0; ni < 4; ni++)
            #pragma unroll
            for (int r = 0; r < 4; r++)
                Pchunk[(quad * 4 + r) * 72 + ni * 16 + col] = f2bf(acc[mi][ni][r] + b1v[ni]);
        __builtin_amdgcn_s_waitcnt(0xc07f);  // lgkmcnt(0): wave-local chunk visible
        __builtin_amdgcn_sched_barrier(0);
        bf16x8 a0 = *(const bf16x8*)&Pchunk[col * 72 + quad * 8];
        bf16x8 a1 = *(const bf16x8*)&Pchunk[col * 72 + 32 + quad * 8];
        __builtin_amdgcn_s_waitcnt(0xc07f);  // reads done before mi+1 overwrites
        __builtin_amdgcn_sched_barrier(0);
        #pragma unroll
        for (int ni = 0; ni < 4; ni++) {
            f32x4 c = (f32x4){0.f, 0.f, 0.f, 0.f};
            c = __builtin_amdgcn_mfma_f32_16x16x32_bf16(a0, bf2r[ni][0], c, 0, 0, 0);
            c = __builtin_amdgcn_mfma_f32_16x16x32_bf16(a1, bf2r[ni][1], c, 0, 0, 0);
            const float bb = B2[ni * 16 + col];
            #pragma unroll
            for (int r = 0; r < 4; r++) qs[mi][ni][r] = elu1(c[r] + bb);
        }
    }

    if (z == 0) {
        float aw[4];
        #pragma unroll
        for (int ni = 0; ni < 4; ni++) aw[ni] = auxA[ni * 16 + col];
        #pragma unroll
        for (int mi = 0; mi < 2; mi++)
            #pragma unroll
            for (int r = 0; r < 4; r++) {
                float pm = 0.f;
                #pragma unroll
                for (int ni = 0; ni < 4; ni++) pm += qs[mi][ni][r] * aw[ni];
                pm += __shfl_xor(pm, 1); pm += __shfl_xor(pm, 2);
                pm += __shfl_xor(pm, 4); pm += __shfl_xor(pm, 8);
                if (col == 0)
                    mB[svecbase + s0 + mi * 16 + quad * 4 + r] = pm + auxS;
            }
        #pragma unroll
        for (int mi = 0; mi < 2; mi++)
            #pragma unroll
            for (int ni = 0; ni < 4; ni++)
                #pragma unroll
                for (int r = 0; r < 4; r++)
                    Qh[(size_t)(rbase + mi * 16 + quad * 4 + r) * D_MODEL
                       + n0 + ni * 16 + col] = f2bf(qs[mi][ni][r] * 0.125f);
    } else if (z == 1) {
        #pragma unroll
        for (int mi = 0; mi < 2; mi++)
            #pragma unroll
            for (int ni = 0; ni < 4; ni++)
                #pragma unroll
                for (int r = 0; r < 4; r++)
                    K2[(size_t)(rbase + mi * 16 + quad * 4 + r) * D_MODEL
                       + n0 + ni * 16 + col] = f2bf(qs[mi][ni][r]);
    } else {
        u16* Tb = W2t;
        __syncthreads();
        #pragma unroll
        for (int p = 0; p < 2; p++) {
            if ((wave >> 1) == p) {
                const int sloc = (wave & 1) * 32;
                #pragma unroll
                for (int mi = 0; mi < 2; mi++)
                    #pragma unroll
                    for (int ni = 0; ni < 4; ni++)
                        #pragma unroll
                        for (int r = 0; r < 4; r++)
                            Tb[(ni * 16 + col) * 72 + sloc + mi * 16 + quad * 4 + r] =
                                f2bf(qs[mi][ni][r]);
            }
            __syncthreads();
            {
                const int d = tid >> 2, seg = tid & 3;
                u16* dst = V2t + (((size_t)b * NH + hh) * DK + d) * S_LEN
                         + (r0 & 1023) + p * 64 + seg * 16;
                *(uint4*)dst = *(const uint4*)&Tb[d * 72 + seg * 16];
                *(uint4*)(dst + 8) = *(const uint4*)&Tb[d * 72 + seg * 16 + 8];
            }
            if (p == 0) __syncthreads();
        }
    }
}

// ---------------------------------------------------------------------------
// MFMA flash attention v3: single-buffered K2s/V2s (two barriers/tile) ->
// LDS 27.6 KB -> ~5 blocks/CU. Fast sigmoid via v_rcp, fast bf16 rounding,
// bitmask mask, direct register reload, setprio around MFMA clusters,
// XCD-aware block swizzle (8 (b,h) groups = 2 MB K/V per XCD L2).
__global__ __launch_bounds__(256) void attn_mfma(
    const u16* __restrict__ Qh, const u16* __restrict__ K2h, const u16* __restrict__ V2t,
    const float* __restrict__ Mq, const float* __restrict__ Uk, const float* __restrict__ Vk,
    const unsigned long long* __restrict__ Mb, u16* __restrict__ X)
{
    __shared__ u16 K2s[64][72];
    __shared__ u16 V2s[64][72];
    __shared__ u16 Ps[4][16][72];

    const int tid = threadIdx.x;
    const int wave = tid >> 6, lane = tid & 63;
    const int col = lane & 15, quad = lane >> 4;

    // XCD swizzle: f%8 -> XCD; give each XCD 8 consecutive (b,h) groups.
    const int f = blockIdx.x;
    const int o = (f & 7) * 128 + (f >> 3);
    const int q0 = (o & 15) * 64;
    const int h = (o >> 4) & 15;
    const int b = o >> 8;

    const size_t hb = ((size_t)(b * NH + h)) * S_LEN * DK;
    const size_t sb = ((size_t)(b * NH + h)) * S_LEN;

    bf16x8 qf0, qf1;
    {
        const u16* qp = Qh + (size_t)(b * S_LEN + q0 + wave * 16 + col) * D_MODEL + h * 64 + quad * 8;
        qf0 = *(const bf16x8*)qp;
        qf1 = *(const bf16x8*)(qp + 32);
    }
    float mqv[4];
    #pragma unroll
    for (int r = 0; r < 4; r++)
        mqv[r] = Mq[sb + q0 + wave * 16 + quad * 4 + r];

    const int srow = tid >> 2, sseg = tid & 3;
    const u16* ksrc = K2h + (size_t)(b * S_LEN + srow) * D_MODEL + h * 64 + sseg * 16;
    const u16* vsrc = V2t + hb + (size_t)srow * S_LEN + sseg * 16;
    const unsigned long long* mbase = Mb
        + ((size_t)b * S_LEN + q0 + wave * 16 + quad * 4) * (S_LEN / 64);
    const unsigned msel0 = 1u << col, msel1 = msel0 << 16;

    // tile-0 prefetch
    uint4 ka = *(const uint4*)(ksrc);
    uint4 kb = *(const uint4*)(ksrc + 8);
    uint4 va = *(const uint4*)(vsrc);
    uint4 vb = *(const uint4*)(vsrc + 8);
    float ku[4], kv[4];
    unsigned long long wm[4];
    #pragma unroll
    for (int nb = 0; nb < 4; nb++) {
        ku[nb] = Uk[sb + nb * 16 + col];
        kv[nb] = Vk[sb + nb * 16 + col];
    }
    #pragma unroll
    for (int r = 0; r < 4; r++) wm[r] = mbase[r * 16];

    float psum[4] = {0.f, 0.f, 0.f, 0.f};
    f32x4 o4[4];
    #pragma unroll
    for (int nb = 0; nb < 4; nb++) o4[nb] = (f32x4){0.f, 0.f, 0.f, 0.f};

    for (int t = 0; t < 16; t++) {
        // stores of tile t (prev iter's barrier B guarantees reads of t-1 done)
        *(uint4*)&K2s[srow][sseg * 16]     = ka;
        *(uint4*)&K2s[srow][sseg * 16 + 8] = kb;
        *(uint4*)&V2s[srow][sseg * 16]     = va;
        *(uint4*)&V2s[srow][sseg * 16 + 8] = vb;
        __syncthreads();  // barrier A: stores visible

        if (t < 15) {   // reload K/V regs for t+1 (latency hidden under QKT+PV)
            const int k1 = (t + 1) * 64;
            const u16* ks = ksrc + (size_t)k1 * D_MODEL;
            const u16* vs = vsrc + k1;
            ka = *(const uint4*)(ks);
            kb = *(const uint4*)(ks + 8);
            va = *(const uint4*)(vs);
            vb = *(const uint4*)(vs + 8);
        }

        // ---- QK^T (Q pre-scaled by 1/8) ----
        __builtin_amdgcn_s_setprio(1);
        f32x4 sc[4];
        #pragma unroll
        for (int nb = 0; nb < 4; nb++) {
            bf16x8 b0 = *(const bf16x8*)&K2s[nb * 16 + col][quad * 8];
            bf16x8 b1 = *(const bf16x8*)&K2s[nb * 16 + col][32 + quad * 8];
            f32x4 c = (f32x4){0.f, 0.f, 0.f, 0.f};
            c = __builtin_amdgcn_mfma_f32_16x16x32_bf16(qf0, b0, c, 0, 0, 0);
            c = __builtin_amdgcn_mfma_f32_16x16x32_bf16(qf1, b1, c, 0, 0, 0);
            sc[nb] = c;
        }
        __builtin_amdgcn_s_setprio(0);

        // ---- gate, mask (bit test), exp (fixed max 0) ----
        #pragma unroll
        for (int nb = 0; nb < 4; nb++) {
            #pragma unroll
            for (int r = 0; r < 4; r++) {
                float e = __expf(-(mqv[r] * ku[nb] + kv[nb]));
                float g = __builtin_amdgcn_rcpf(1.f + e);
                float sv = sc[nb][r] * g;
                const unsigned bits = (nb < 2) ? (unsigned)wm[r]
                                               : (unsigned)(wm[r] >> 32);
                sv = (bits & ((nb & 1) ? msel1 : msel0)) ? sv : -30.f;
                float p = __expf(sv);
                psum[r] += p;
                Ps[wave][quad * 4 + r][nb * 16 + col] = f2bf_fast(p);
            }
        }
        if (t < 15) {   // reload gate/mask regs for t+1 (dead after gate loop)
            const int k1 = (t + 1) * 64;
            #pragma unroll
            for (int nb = 0; nb < 4; nb++) {
                ku[nb] = Uk[sb + k1 + nb * 16 + col];
                kv[nb] = Vk[sb + k1 + nb * 16 + col];
            }
            #pragma unroll
            for (int r = 0; r < 4; r++) wm[r] = mbase[r * 16 + t + 1];
        }
        __builtin_amdgcn_s_waitcnt(0xc07f);  // lgkmcnt(0); vm prefetch in flight
        __builtin_amdgcn_sched_barrier(0);
        bf16x8 a0 = *(const bf16x8*)&Ps[wave][col][quad * 8];
        bf16x8 a1 = *(const bf16x8*)&Ps[wave][col][32 + quad * 8];

        // ---- PV ----
        __builtin_amdgcn_s_setprio(1);
        #pragma unroll
        for (int nb = 0; nb < 4; nb++) {
            bf16x8 b0 = *(const bf16x8*)&V2s[nb * 16 + col][quad * 8];
            bf16x8 b1 = *(const bf16x8*)&V2s[nb * 16 + col][32 + quad * 8];
            o4[nb] = __builtin_amdgcn_mfma_f32_16x16x32_bf16(a0, b0, o4[nb], 0, 0, 0);
            o4[nb] = __builtin_amdgcn_mfma_f32_16x16x32_bf16(a1, b1, o4[nb], 0, 0, 0);
        }
        __builtin_amdgcn_s_setprio(0);
        __syncthreads();  // barrier B: all reads done; next stores safe
    }

    #pragma unroll
    for (int r = 0; r < 4; r++) {
        float t = psum[r];
        t += __shfl_xor(t, 1);
        t += __shfl_xor(t, 2);
        t += __shfl_xor(t, 4);
        t += __shfl_xor(t, 8);
        float inv = __builtin_amdgcn_rcpf(t);
        u16* xp = X + (size_t)(b * S_LEN + q0 + wave * 16 + quad * 4 + r) * D_MODEL + h * 64 + col;
        #pragma unroll
        for (int nb = 0; nb < 4; nb++)
            xp[nb * 16] = f2bf_fast(o4[nb][r] * inv);
    }
}

// ---------------------------------------------------------------------------
// out_gemm v2: C(f32) = A(bf16) @ WT^T + bias. 128x64 tiles, grid (32,16)
// = 512 blocks (2/CU). Per wave: 32 rows x 64 cols, acc[2][4], 8 MFMA and
// 6 ds_read_b128 per K-step. Same XOR swizzle as proj_fused v4.
__global__ __launch_bounds__(256) void out_gemm(
    const u16* __restrict__ A, const u16* __restrict__ WT,
    const float* __restrict__ bias, float* __restrict__ C)
{
    __shared__ u16 As[128 * 32];
    __shared__ u16 Bs[64 * 32];

    const int tid = threadIdx.x;
    const int wave = tid >> 6, lane = tid & 63;
    const int col = lane & 15, quad = lane >> 4;
    const int r0 = blockIdx.x * 128, n0 = blockIdx.y * 64;

    const int srow = lane >> 2;
    const int sg = ((lane & 3) ^ ((lane >> 3) & 3)) * 8;
    const u16* ap = A + (size_t)(r0 + wave * 32 + srow) * D_MODEL + sg;
    const u16* bp = WT + (size_t)(n0 + wave * 16 + srow) * D_MODEL + sg;
    u16* adst0 = As + (wave * 32) * 32;  u16* adst1 = adst0 + 512;
    u16* bdst = Bs + wave * 16 * 32;

    f32x4 acc[2][4];
    #pragma unroll
    for (int i = 0; i < 2; i++)
        #pragma unroll
        for (int j = 0; j < 4; j++)
            acc[i][j] = (f32x4){0.f, 0.f, 0.f, 0.f};

    const int gsw = (quad ^ ((col >> 1) & 3)) * 8;

    for (int k0 = 0; k0 < D_MODEL; k0 += 32) {
        if (k0) __syncthreads();
        async16(ap + k0, adst0);
        async16(ap + (size_t)16 * D_MODEL + k0, adst1);
        async16(bp + k0, bdst);
        __syncthreads();
        const u16* Ab = As + (wave * 32 + col) * 32 + gsw;
        const u16* Bb = Bs + col * 32 + gsw;
        bf16x8 af[2], bfr[4];
        #pragma unroll
        for (int mi = 0; mi < 2; mi++) af[mi] = *(const bf16x8*)(Ab + mi * 512);
        #pragma unroll
        for (int ni = 0; ni < 4; ni++) bfr[ni] = *(const bf16x8*)(Bb + ni * 512);
        #pragma unroll
        for (int mi = 0; mi < 2; mi++)
            #pragma unroll
            for (int ni = 0; ni < 4; ni++)
                acc[mi][ni] = __builtin_amdgcn_mfma_f32_16x16x32_bf16(af[mi], bfr[ni], acc[mi][ni], 0, 0, 0);
    }

    #pragma unroll
    for (int mi = 0; mi < 2; mi++)
        #pragma unroll
        for (int ni = 0; ni < 4; ni++) {
            const int gr = r0 + wave * 32 + mi * 16 + quad * 4;
            const int gc = n0 + ni * 16 + col;
            const float bb = bias[gc];
            #pragma unroll
            for (int r = 0; r < 4; r++)
                C[(size_t)(gr + r) * D_MODEL + gc] = acc[mi][ni][r] + bb;
        }
}

// ---------------------------------------------------------------------------
extern "C" void kernel_launch(void* const* d_in, const int* in_sizes, int n_in,
                              void* d_out, int out_size, void* d_ws, size_t ws_size,
                              hipStream_t stream) {
    (void)in_sizes; (void)n_in; (void)out_size; (void)ws_size;
    const float* query = (const float*)d_in[0];
    const float* key_  = (const float*)d_in[1];
    const float* value = (const float*)d_in[2];
    const int*   mask  = (const int*)d_in[3];
    const float* wq = (const float*)d_in[4];  const float* bq = (const float*)d_in[5];
    const float* wk = (const float*)d_in[6];  const float* bk = (const float*)d_in[7];
    const float* wv = (const float*)d_in[8];  const float* bv = (const float*)d_in[9];
    const float* wo = (const float*)d_in[10]; const float* bo = (const float*)d_in[11];
    const float* spatial_w = (const float*)d_in[12]; const float* spatial_b = (const float*)d_in[13];
    const float* qproj_w   = (const float*)d_in[14]; const float* qproj_b   = (const float*)d_in[15];
    const float* kproj_w   = (const float*)d_in[16]; const float* kproj_b   = (const float*)d_in[17];
    const float* vlin_w    = (const float*)d_in[18]; const float* vlin_b    = (const float*)d_in[19];
    const float* chan_w    = (const float*)d_in[20]; const float* chan_b    = (const float*)d_in[21];
    float* out = (float*)d_out;

    char* ws = (char*)d_ws;
    u16* Qh  = (u16*)ws;                          // 8 MB [B,S,H,DK] bf16 (pre-scaled 1/8)
    u16* K2  = (u16*)(ws + ((size_t)8  << 20));   // 8 MB [B,S,H,DK] bf16
    u16* Xb  = (u16*)(ws + ((size_t)16 << 20));   // 8 MB [B,S,D] bf16 (attn out)
    u16* WT  = (u16*)(ws + ((size_t)24 << 20));   // 8 MB: 4 transposed weights
    u16* V2t = (u16*)(ws + ((size_t)32 << 20));   // 8 MB [B,H,DK,S] bf16
    float* mB = (float*)(ws + ((size_t)40 << 20));
    float* uB = mB + (size_t)BATCH * NH * S_LEN;
    float* vB = uB + (size_t)BATCH * NH * S_LEN;
    unsigned long long* Mbits = (unsigned long long*)(ws + ((size_t)41 << 20)); // 512 KB
    u16* Xbf = (u16*)(ws + ((size_t)42 << 20));   // 24 MB: 3x [B,S,D] bf16 inputs
    const size_t WSZ = (size_t)D_MODEL * D_MODEL;
    const size_t XSZ = (size_t)MROWS * D_MODEL;

    prep<<<dim3(9216), 256, 0, stream>>>(wq, wk, wv, wo, WT,
        query, key_, value, Xbf, mask, Mbits);
    proj_fused<<<dim3(32, 16, 3), 256, 0, stream>>>(Xbf, Xbf + XSZ, Xbf + 2 * XSZ,
        WT, WT + WSZ, WT + 2 * WSZ, bq, bk, bv,
        spatial_w, spatial_b, qproj_w, qproj_b, kproj_w, kproj_b,
        vlin_w, vlin_b, chan_w, chan_b,
        Qh, K2, V2t, mB, uB, vB);
    attn_mfma<<<dim3(1024), 256, 0, stream>>>(Qh, K2, V2t, mB, uB, vB, Mbits, Xb);
    out_gemm<<<dim3(32, 16), 256, 0, stream>>>(Xb, WT + 3 * WSZ, bo, out);
}

// Round 10
// 275.951 us; speedup vs baseline: 1.0211x; 1.0038x over previous
//
#include <hip/hip_runtime.h>
#include <math.h>

#define D_MODEL 1024
#define NH 16
#define DK 64
#define S_LEN 1024
#define BATCH 4
#define MROWS (BATCH * S_LEN)  // 4096

typedef short bf16x8 __attribute__((ext_vector_type(8)));
typedef float f32x4 __attribute__((ext_vector_type(4)));
typedef unsigned short u16;

__device__ __forceinline__ float elu1(float x) {
    return x > 0.f ? x : (expf(x) - 1.f);
}

__device__ __forceinline__ u16 f2bf(float f) {
    union { float f; unsigned u; } v; v.f = f;
    unsigned u = v.u;
    return (u16)((u + 0x7fffu + ((u >> 16) & 1u)) >> 16);
}

// round-to-nearest (ties up) bf16 cast: 2 VALU ops instead of 4.
__device__ __forceinline__ u16 f2bf_fast(float f) {
    union { float f; unsigned u; } v; v.f = f;
    return (u16)((v.u + 0x8000u) >> 16);
}

__device__ __forceinline__ void async16(const void* g, void* l) {
    __builtin_amdgcn_global_load_lds(
        (const __attribute__((address_space(1))) unsigned int*)g,
        (__attribute__((address_space(3))) unsigned int*)l,
        16, 0, 0);
}

// ---------------------------------------------------------------------------
// prep: fused cast_wt + cast_x + mask_pack (all independent, all memory-bound)
// in ONE dispatch. Blocks 0..1023: weight transpose-cast; 1024..7167: X cast;
// 7168..9215: mask bitpack. Branches are block-uniform.
__global__ __launch_bounds__(256) void prep(
    const float* __restrict__ wq, const float* __restrict__ wk,
    const float* __restrict__ wv, const float* __restrict__ wo,
    u16* __restrict__ WT,
    const float* __restrict__ Xq, const float* __restrict__ Xk,
    const float* __restrict__ Xv, u16* __restrict__ Xb,
    const int* __restrict__ mask, unsigned long long* __restrict__ Mb)
{
    __shared__ float T[64][65];
    const int bid = blockIdx.x;
    const int tid = threadIdx.x;

    if (bid < 1024) {
        // ---- cast_wt: W f32 [k][n] -> WT bf16 [n][k] ----
        const int z = bid >> 8;
        const int rem = bid & 255;
        const int n0 = (rem & 15) * 64, k0 = (rem >> 4) * 64;
        const float* W = (z == 0) ? wq : ((z == 1) ? wk : ((z == 2) ? wv : wo));
        u16* O = WT + (size_t)z * D_MODEL * D_MODEL;
        const int r = tid >> 4, c4 = (tid & 15) * 4;
        #pragma unroll
        for (int p = 0; p < 4; p++) {
            float4 v = *(const float4*)&W[(size_t)(k0 + r + p * 16) * D_MODEL + n0 + c4];
            T[r + p * 16][c4 + 0] = v.x; T[r + p * 16][c4 + 1] = v.y;
            T[r + p * 16][c4 + 2] = v.z; T[r + p * 16][c4 + 3] = v.w;
        }
        __syncthreads();
        #pragma unroll
        for (int p = 0; p < 4; p++) {
            const int i = r + p * 16;
            ushort4 o4;
            o4.x = f2bf(T[c4 + 0][i]); o4.y = f2bf(T[c4 + 1][i]);
            o4.z = f2bf(T[c4 + 2][i]); o4.w = f2bf(T[c4 + 3][i]);
            *(ushort4*)&O[(size_t)(n0 + i) * D_MODEL + k0 + c4] = o4;
        }
    } else if (bid < 1024 + 6144) {
        // ---- cast_x: X f32 -> bf16 ----
        const int idx = bid - 1024;
        const int z = idx >> 11;            // 0..2
        const int bx = idx & 2047;
        const float* X = (z == 0) ? Xq : ((z == 1) ? Xk : Xv);
        u16* O = Xb + (size_t)z * MROWS * D_MODEL;
        const size_t i = ((size_t)bx * 256 + tid) * 8;
        float4 a = *(const float4*)&X[i];
        float4 b = *(const float4*)&X[i + 4];
        ushort4 o0, o1;
        o0.x = f2bf(a.x); o0.y = f2bf(a.y); o0.z = f2bf(a.z); o0.w = f2bf(a.w);
        o1.x = f2bf(b.x); o1.y = f2bf(b.y); o1.z = f2bf(b.z); o1.w = f2bf(b.w);
        *(ushort4*)&O[i] = o0;
        *(ushort4*)&O[i + 4] = o1;
    } else {
        // ---- mask_pack: int32 [B][S][S] -> u64 bitmask via ballot ----
        const int bx = bid - 7168;
        const int gw = (bx * 256 + tid) >> 6;   // 0..8191
        const int lane = tid & 63;
        int v[8];
        #pragma unroll
        for (int i = 0; i < 8; i++)
            v[i] = mask[((size_t)gw + (size_t)i * 8192) * 64 + lane];
        #pragma unroll
        for (int i = 0; i < 8; i++) {
            unsigned long long bits = __ballot(v[i] != 0);
            if (lane == 0) Mb[(size_t)gw + (size_t)i * 8192] = bits;
        }
    }
}

// ---------------------------------------------------------------------------
// proj_fused v6: 128x64 tile, one head per block, BK=64.
// 16 K-steps: 16 MFMA + 12 ds_read + 6 async16 per wave between drains.
// Swizzle for 128B rows: src granule (l&7)^((l>>3)&7), read granule
// (ks*4+quad)^(col&7) -- bijective per 8-row stripe, conflict-free b128.
__global__ __launch_bounds__(256) void proj_fused(
    const u16* __restrict__ Xq, const u16* __restrict__ Xk, const u16* __restrict__ Xv,
    const u16* __restrict__ WTq, const u16* __restrict__ WTk, const u16* __restrict__ WTv,
    const float* __restrict__ bq, const float* __restrict__ bk, const float* __restrict__ bv,
    const float* __restrict__ spatial_w, const float* __restrict__ spatial_b,
    const float* __restrict__ qproj_w, const float* __restrict__ qproj_b,
    const float* __restrict__ kproj_w, const float* __restrict__ kproj_b,
    const float* __restrict__ vlin_w, const float* __restrict__ vlin_b,
    const float* __restrict__ chan_w, const float* __restrict__ chan_b,
    u16* __restrict__ Qh, u16* __restrict__ K2, u16* __restrict__ V2t,
    float* __restrict__ mB, float* __restrict__ uB, float* __restrict__ vB)
{
    __shared__ __align__(16) u16 smem[16896];
    __shared__ float auxA[64];
    __shared__ float auxS;

    u16* As = smem;
    u16* Bs = smem + 8192;
    u16* W2t = smem + 12288;

    const int z = blockIdx.z;
    const u16* X = (z == 0) ? Xq : ((z == 1) ? Xk : Xv);
    const u16* WT = (z == 0) ? WTq : ((z == 1) ? WTk : WTv);
    const float* B1 = (z == 0) ? bq : ((z == 1) ? bk : bv);
    const float* W2 = (z == 0) ? spatial_w : ((z == 1) ? kproj_w : vlin_w);
    const float* B2 = (z == 0) ? spatial_b : ((z == 1) ? kproj_b : vlin_b);

    const int tid = threadIdx.x;
    const int wave = tid >> 6, lane = tid & 63;
    const int col = lane & 15, quad = lane >> 4;
    const int r0 = blockIdx.x * 128;
    const int hh = blockIdx.y;          // head (one per block)
    const int n0 = hh * 64;

    // ---- stage W2t (transposed bf16) + aux ----
    #pragma unroll
    for (int p = 0; p < 4; p++) {
        int idx = p * 256 + tid;
        int f = idx >> 4, e4 = (idx & 15) * 4;
        float4 w4 = *(const float4*)&W2[f * 64 + e4];
        W2t[(e4 + 0) * 72 + f] = f2bf(w4.x);
        W2t[(e4 + 1) * 72 + f] = f2bf(w4.y);
        W2t[(e4 + 2) * 72 + f] = f2bf(w4.z);
        W2t[(e4 + 3) * 72 + f] = f2bf(w4.w);
    }
    if (z == 0) {
        {
            int row = tid >> 2, part = tid & 3;
            float s = 0.f;
            for (int e = part * 16; e < part * 16 + 16; e++) s += qproj_w[row * 64 + e];
            s += __shfl_xor(s, 1);
            s += __shfl_xor(s, 2);
            if (part == 0) auxA[row] = s * (1.f / 64.f);
        }
        if (tid < 64) {
            float s = qproj_b[tid];
            #pragma unroll
            for (int m = 1; m < 64; m <<= 1) s += __shfl_xor(s, m);
            if (tid == 0) auxS = s * (1.f / 64.f);
        }
    }

    // ---- phase 1: GEMM 128x64, BK=64, async16 staging + XOR swizzle ----
    const int srow8 = lane >> 3;                   // 0..7
    const int sg = ((lane & 7) ^ srow8) * 8;       // swizzled src granule (u16)

    const u16* ap = X + (size_t)(r0 + wave * 32 + srow8) * D_MODEL + sg;
    const u16* bp = WT + (size_t)(n0 + wave * 16 + srow8) * D_MODEL + sg;
    u16* adst = As + (wave * 32) * 64;
    u16* bdst = Bs + (wave * 16) * 64;

    f32x4 acc[2][4];
    #pragma unroll
    for (int i = 0; i < 2; i++)
        #pragma unroll
        for (int j = 0; j < 4; j++)
            acc[i][j] = (f32x4){0.f, 0.f, 0.f, 0.f};

    for (int k0 = 0; k0 < D_MODEL; k0 += 64) {
        if (k0) __syncthreads();
        #pragma unroll
        for (int i = 0; i < 4; i++)
            async16(ap + (size_t)(i * 8) * D_MODEL + k0, adst + i * 512);
        #pragma unroll
        for (int j = 0; j < 2; j++)
            async16(bp + (size_t)(j * 8) * D_MODEL + k0, bdst + j * 512);
        __syncthreads();
        #pragma unroll
        for (int ks = 0; ks < 2; ks++) {
            const int gk = ((ks * 4 + quad) ^ (col & 7)) * 8;
            const u16* Abase = As + (wave * 32 + col) * 64 + gk;
            const u16* Bbase = Bs + col * 64 + gk;
            bf16x8 af[2], bfr[4];
            #pragma unroll
            for (int mi = 0; mi < 2; mi++) af[mi] = *(const bf16x8*)(Abase + mi * 1024);
            #pragma unroll
            for (int ni = 0; ni < 4; ni++) bfr[ni] = *(const bf16x8*)(Bbase + ni * 1024);
            #pragma unroll
            for (int mi = 0; mi < 2; mi++)
                #pragma unroll
                for (int ni = 0; ni < 4; ni++)
                    acc[mi][ni] = __builtin_amdgcn_mfma_f32_16x16x32_bf16(af[mi], bfr[ni], acc[mi][ni], 0, 0, 0);
        }
    }

    // ---- phase 2: epilogue ----
    float b1v[4];
    #pragma unroll
    for (int ni = 0; ni < 4; ni++) b1v[ni] = B1[n0 + ni * 16 + col];

    const int rbase = r0 + wave * 32;
    const int b = r0 >> 10;
    const int s0 = (r0 & 1023) + wave * 32;
    const size_t svecbase = ((size_t)b * NH + hh) * S_LEN;

    if (z == 1) {
        float cw[4], cb[4];
        #pragma unroll
        for (int ni = 0; ni < 4; ni++) { cw[ni] = chan_w[ni * 16 + col]; cb[ni] = chan_b[ni * 16 + col]; }
        #pragma unroll
        for (int mi = 0; mi < 2; mi++)
            #pragma unroll
            for (int r = 0; r < 4; r++) {
                float su = 0.f, sv = 0.f;
                #pragma unroll
                for (int ni = 0; ni < 4; ni++) {
                    float p = acc[mi][ni][r] + b1v[ni];
                    su += p * cw[ni];
                    sv += p * cb[ni];
                }
                su += __shfl_xor(su, 1); su += __shfl_xor(su, 2);
                su += __shfl_xor(su, 4); su += __shfl_xor(su, 8);
                sv += __shfl_xor(sv, 1); sv += __shfl_xor(sv, 2);
                sv += __shfl_xor(sv, 4); sv += __shfl_xor(sv, 8);
                if (col == 0) {
                    const size_t idx = svecbase + s0 + mi * 16 + quad * 4 + r;
                    uB[idx] = su;
                    vB[idx] = sv;
                }
            }
    }

    __syncthreads();  // phase-1 As/Bs reads done; safe to alias Pchunk

    u16* Pchunk = smem + wave * 1536;
    bf16x8 bf2r[4][2];
    #pragma unroll
    for (int ni = 0; ni < 4; ni++) {
        bf2r[ni][0] = *(const bf16x8*)&W2t[(ni * 16 + col) * 72 + quad * 8];
        bf2r[ni][1] = *(const bf16x8*)&W2t[(ni * 16 + col) * 72 + 32 + quad * 8];
    }
    float qs[2][4][4];
    #pragma unroll
    for (int mi = 0; mi < 2; mi++) {
        #pragma unroll
        for (int ni = 0; ni < 4; ni++)
            #pragma unroll
            for (int r = 0; r < 4; r++)
                Pchunk[(quad * 4 + r) * 72 + ni * 16 + col] = f2bf(acc[mi][ni][r] + b1v[ni]);
        __builtin_amdgcn_s_waitcnt(0xc07f);  // lgkmcnt(0): wave-local chunk visible
        __builtin_amdgcn_sched_barrier(0);
        bf16x8 a0 = *(const bf16x8*)&Pchunk[col * 72 + quad * 8];
        bf16x8 a1 = *(const bf16x8*)&Pchunk[col * 72 + 32 + quad * 8];
        __builtin_amdgcn_s_waitcnt(0xc07f);  // reads done before mi+1 overwrites
        __builtin_amdgcn_sched_barrier(0);
        #pragma unroll
        for (int ni = 0; ni < 4; ni++) {
            f32x4 c = (f32x4){0.f, 0.f, 0.f, 0.f};
            c = __builtin_amdgcn_mfma_f32_16x16x32_bf16(a0, bf2r[ni][0], c, 0, 0, 0);
            c = __builtin_amdgcn_mfma_f32_16x16x32_bf16(a1, bf2r[ni][1], c, 0, 0, 0);
            const float bb = B2[ni * 16 + col];
            #pragma unroll
            for (int r = 0; r < 4; r++) qs[mi][ni][r] = elu1(c[r] + bb);
        }
    }

    if (z == 0) {
        float aw[4];
        #pragma unroll
        for (int ni = 0; ni < 4; ni++) aw[ni] = auxA[ni * 16 + col];
        #pragma unroll
        for (int mi = 0; mi < 2; mi++)
            #pragma unroll
            for (int r = 0; r < 4; r++) {
                float pm = 0.f;
                #pragma unroll
                for (int ni = 0; ni < 4; ni++) pm += qs[mi][ni][r] * aw[ni];
                pm += __shfl_xor(pm, 1); pm += __shfl_xor(pm, 2);
                pm += __shfl_xor(pm, 4); pm += __shfl_xor(pm, 8);
                if (col == 0)
                    mB[svecbase + s0 + mi * 16 + quad * 4 + r] = pm + auxS;
            }
        #pragma unroll
        for (int mi = 0; mi < 2; mi++)
            #pragma unroll
            for (int ni = 0; ni < 4; ni++)
                #pragma unroll
                for (int r = 0; r < 4; r++)
                    Qh[(size_t)(rbase + mi * 16 + quad * 4 + r) * D_MODEL
                       + n0 + ni * 16 + col] = f2bf(qs[mi][ni][r] * 0.125f);
    } else if (z == 1) {
        #pragma unroll
        for (int mi = 0; mi < 2; mi++)
            #pragma unroll
            for (int ni = 0; ni < 4; ni++)
                #pragma unroll
                for (int r = 0; r < 4; r++)
                    K2[(size_t)(rbase + mi * 16 + quad * 4 + r) * D_MODEL
                       + n0 + ni * 16 + col] = f2bf(qs[mi][ni][r]);
    } else {
        u16* Tb = W2t;
        __syncthreads();
        #pragma unroll
        for (int p = 0; p < 2; p++) {
            if ((wave >> 1) == p) {
                const int sloc = (wave & 1) * 32;
                #pragma unroll
                for (int mi = 0; mi < 2; mi++)
                    #pragma unroll
                    for (int ni = 0; ni < 4; ni++)
                        #pragma unroll
                        for (int r = 0; r < 4; r++)
                            Tb[(ni * 16 + col) * 72 + sloc + mi * 16 + quad * 4 + r] =
                                f2bf(qs[mi][ni][r]);
            }
            __syncthreads();
            {
                const int d = tid >> 2, seg = tid & 3;
                u16* dst = V2t + (((size_t)b * NH + hh) * DK + d) * S_LEN
                         + (r0 & 1023) + p * 64 + seg * 16;
                *(uint4*)dst = *(const uint4*)&Tb[d * 72 + seg * 16];
                *(uint4*)(dst + 8) = *(const uint4*)&Tb[d * 72 + seg * 16 + 8];
            }
            if (p == 0) __syncthreads();
        }
    }
}

// ---------------------------------------------------------------------------
// MFMA flash attention v4: QBLK=128 (two 64-row Q chunks per block, 512
// blocks). K/V staging, barriers, and K/V global reads HALVED per unit
// work vs v3. Gate params (Uk/Vk/Mb) loaded per-tile (L2-resident) instead
// of cross-tile prefetch to keep VGPR < 128 (4 waves/SIMD boundary).
__global__ __launch_bounds__(256) void attn_mfma(
    const u16* __restrict__ Qh, const u16* __restrict__ K2h, const u16* __restrict__ V2t,
    const float* __restrict__ Mq, const float* __restrict__ Uk, const float* __restrict__ Vk,
    const unsigned long long* __restrict__ Mb, u16* __restrict__ X)
{
    __shared__ u16 K2s[64][72];
    __shared__ u16 V2s[64][72];
    __shared__ u16 Ps[4][16][72];

    const int tid = threadIdx.x;
    const int wave = tid >> 6, lane = tid & 63;
    const int col = lane & 15, quad = lane >> 4;

    // XCD swizzle: 512 blocks = 8 XCDs x 64. Each XCD gets 64 consecutive
    // o's = 8 q-tiles x 8 heads (2 MB K/V in its L2).
    const int f = blockIdx.x;
    const int o = (f & 7) * 64 + (f >> 3);
    const int q0 = (o & 7) * 128;
    const int h = (o >> 3) & 15;
    const int b = o >> 7;

    const size_t hb = ((size_t)(b * NH + h)) * S_LEN * DK;
    const size_t sb = ((size_t)(b * NH + h)) * S_LEN;

    bf16x8 qf0[2], qf1[2];
    float mqv[2][4];
    #pragma unroll
    for (int qc = 0; qc < 2; qc++) {
        const u16* qp = Qh + (size_t)(b * S_LEN + q0 + qc * 64 + wave * 16 + col) * D_MODEL
                      + h * 64 + quad * 8;
        qf0[qc] = *(const bf16x8*)qp;
        qf1[qc] = *(const bf16x8*)(qp + 32);
        #pragma unroll
        for (int r = 0; r < 4; r++)
            mqv[qc][r] = Mq[sb + q0 + qc * 64 + wave * 16 + quad * 4 + r];
    }

    const int srow = tid >> 2, sseg = tid & 3;
    const u16* ksrc = K2h + (size_t)(b * S_LEN + srow) * D_MODEL + h * 64 + sseg * 16;
    const u16* vsrc = V2t + hb + (size_t)srow * S_LEN + sseg * 16;
    const unsigned long long* mb0 = Mb
        + ((size_t)b * S_LEN + q0 + wave * 16 + quad * 4) * (S_LEN / 64);
    const unsigned msel0 = 1u << col, msel1 = msel0 << 16;

    // tile-0 prefetch (K/V only; gate params loaded per-tile, L2-resident)
    uint4 ka = *(const uint4*)(ksrc);
    uint4 kb = *(const uint4*)(ksrc + 8);
    uint4 va = *(const uint4*)(vsrc);
    uint4 vb = *(const uint4*)(vsrc + 8);

    float psum[2][4];
    f32x4 o4[2][4];
    #pragma unroll
    for (int qc = 0; qc < 2; qc++) {
        #pragma unroll
        for (int r = 0; r < 4; r++) psum[qc][r] = 0.f;
        #pragma unroll
        for (int nb = 0; nb < 4; nb++) o4[qc][nb] = (f32x4){0.f, 0.f, 0.f, 0.f};
    }

    for (int t = 0; t < 16; t++) {
        *(uint4*)&K2s[srow][sseg * 16]     = ka;
        *(uint4*)&K2s[srow][sseg * 16 + 8] = kb;
        *(uint4*)&V2s[srow][sseg * 16]     = va;
        *(uint4*)&V2s[srow][sseg * 16 + 8] = vb;

        // gate params for this tile (L2-resident; issued before barrier so
        // latency hides under the barrier + QK^T)
        float ku[4], kv[4];
        #pragma unroll
        for (int nb = 0; nb < 4; nb++) {
            ku[nb] = Uk[sb + t * 64 + nb * 16 + col];
            kv[nb] = Vk[sb + t * 64 + nb * 16 + col];
        }
        __syncthreads();  // barrier A: stores visible

        if (t < 15) {   // reload K/V regs for t+1 (latency hidden under compute)
            const int k1 = (t + 1) * 64;
            const u16* ks = ksrc + (size_t)k1 * D_MODEL;
            const u16* vs = vsrc + k1;
            ka = *(const uint4*)(ks);
            kb = *(const uint4*)(ks + 8);
            va = *(const uint4*)(vs);
            vb = *(const uint4*)(vs + 8);
        }

        #pragma unroll
        for (int qc = 0; qc < 2; qc++) {
            // mask bits for this (q-chunk, tile)
            unsigned long long wm[4];
            #pragma unroll
            for (int r = 0; r < 4; r++)
                wm[r] = mb0[(qc * 64 + r * 4 / 4 * 0 + r) * 16 + t + (size_t)qc * 64 * 16 - (size_t)qc * 64 * 16 + (size_t)qc * 1024 - (size_t)qc * 1024];
            // (simplified below — see note)
            #pragma unroll
            for (int r = 0; r < 4; r++)
                wm[r] = mb0[((size_t)qc * 64 + r) * 16 + t];

            // ---- QK^T (Q pre-scaled by 1/8) ----
            __builtin_amdgcn_s_setprio(1);
            f32x4 sc[4];
            #pragma unroll
            for (int nb = 0; nb < 4; nb++) {
                bf16x8 b0 = *(const bf16x8*)&K2s[nb * 16 + col][quad * 8];
                bf16x8 b1 = *(const bf16x8*)&K2s[nb * 16 + col][32 + quad * 8];
                f32x4 c = (f32x4){0.f, 0.f, 0.f, 0.f};
                c = __builtin_amdgcn_mfma_f32_16x16x32_bf16(qf0[qc], b0, c, 0, 0, 0);
                c = __builtin_amdgcn_mfma_f32_16x16x32_bf16(qf1[qc], b1, c, 0, 0, 0);
                sc[nb] = c;
            }
            __builtin_amdgcn_s_setprio(0);

            // ---- gate, mask (bit test), exp (fixed max 0) ----
            #pragma unroll
            for (int nb = 0; nb < 4; nb++) {
                #pragma unroll
                for (int r = 0; r < 4; r++) {
                    float e = __expf(-(mqv[qc][r] * ku[nb] + kv[nb]));
                    float g = __builtin_amdgcn_rcpf(1.f + e);
                    float sv = sc[nb][r] * g;
                    const unsigned bits = (nb < 2) ? (unsigned)wm[r]
                                                   : (unsigned)(wm[r] >> 32);
                    sv = (bits & ((nb & 1) ? msel1 : msel0)) ? sv : -30.f;
                    float p = __expf(sv);
                    psum[qc][r] += p;
                    Ps[wave][quad * 4 + r][nb * 16 + col] = f2bf_fast(p);
                }
            }
            __builtin_amdgcn_s_waitcnt(0xc07f);  // lgkmcnt(0): Ps writes visible
            __builtin_amdgcn_sched_barrier(0);
            bf16x8 a0 = *(const bf16x8*)&Ps[wave][col][quad * 8];
            bf16x8 a1 = *(const bf16x8*)&Ps[wave][col][32 + quad * 8];
            __builtin_amdgcn_s_waitcnt(0xc07f);  // reads done before qc+1 overwrites
            __builtin_amdgcn_sched_barrier(0);

            // ---- PV ----
            __builtin_amdgcn_s_setprio(1);
            #pragma unroll
            for (int nb = 0; nb < 4; nb++) {
                bf16x8 b0 = *(const bf16x8*)&V2s[nb * 16 + col][quad * 8];
                bf16x8 b1 = *(const bf16x8*)&V2s[nb * 16 + col][32 + quad * 8];
                o4[qc][nb] = __builtin_amdgcn_mfma_f32_16x16x32_bf16(a0, b0, o4[qc][nb], 0, 0, 0);
                o4[qc][nb] = __builtin_amdgcn_mfma_f32_16x16x32_bf16(a1, b1, o4[qc][nb], 0, 0, 0);
            }
            __builtin_amdgcn_s_setprio(0);
        }
        __syncthreads();  // barrier B: all reads done; next stores safe
    }

    #pragma unroll
    for (int qc = 0; qc < 2; qc++)
        #pragma unroll
        for (int r = 0; r < 4; r++) {
            float t = psum[qc][r];
            t += __shfl_xor(t, 1);
            t += __shfl_xor(t, 2);
            t += __shfl_xor(t, 4);
            t += __shfl_xor(t, 8);
            float inv = __builtin_amdgcn_rcpf(t);
            u16* xp = X + (size_t)(b * S_LEN + q0 + qc * 64 + wave * 16 + quad * 4 + r) * D_MODEL
                    + h * 64 + col;
            #pragma unroll
            for (int nb = 0; nb < 4; nb++)
                xp[nb * 16] = f2bf_fast(o4[qc][nb][r] * inv);
        }
}

// ---------------------------------------------------------------------------
// out_gemm v2: C(f32) = A(bf16) @ WT^T + bias. 128x64 tiles, grid (32,16)
// = 512 blocks (2/CU). Per wave: 32 rows x 64 cols, acc[2][4], 8 MFMA and
// 6 ds_read_b128 per K-step. Same XOR swizzle as proj_fused v4.
__global__ __launch_bounds__(256) void out_gemm(
    const u16* __restrict__ A, const u16* __restrict__ WT,
    const float* __restrict__ bias, float* __restrict__ C)
{
    __shared__ u16 As[128 * 32];
    __shared__ u16 Bs[64 * 32];

    const int tid = threadIdx.x;
    const int wave = tid >> 6, lane = tid & 63;
    const int col = lane & 15, quad = lane >> 4;
    const int r0 = blockIdx.x * 128, n0 = blockIdx.y * 64;

    const int srow = lane >> 2;
    const int sg = ((lane & 3) ^ ((lane >> 3) & 3)) * 8;
    const u16* ap = A + (size_t)(r0 + wave * 32 + srow) * D_MODEL + sg;
    const u16* bp = WT + (size_t)(n0 + wave * 16 + srow) * D_MODEL + sg;
    u16* adst0 = As + (wave * 32) * 32;  u16* adst1 = adst0 + 512;
    u16* bdst = Bs + wave * 16 * 32;

    f32x4 acc[2][4];
    #pragma unroll
    for (int i = 0; i < 2; i++)
        #pragma unroll
        for (int j = 0; j < 4; j++)
            acc[i][j] = (f32x4){0.f, 0.f, 0.f, 0.f};

    const int gsw = (quad ^ ((col >> 1) & 3)) * 8;

    for (int k0 = 0; k0 < D_MODEL; k0 += 32) {
        if (k0) __syncthreads();
        async16(ap + k0, adst0);
        async16(ap + (size_t)16 * D_MODEL + k0, adst1);
        async16(bp + k0, bdst);
        __syncthreads();
        const u16* Ab = As + (wave * 32 + col) * 32 + gsw;
        const u16* Bb = Bs + col * 32 + gsw;
        bf16x8 af[2], bfr[4];
        #pragma unroll
        for (int mi = 0; mi < 2; mi++) af[mi] = *(const bf16x8*)(Ab + mi * 512);
        #pragma unroll
        for (int ni = 0; ni < 4; ni++) bfr[ni] = *(const bf16x8*)(Bb + ni * 512);
        #pragma unroll
        for (int mi = 0; mi < 2; mi++)
            #pragma unroll
            for (int ni = 0; ni < 4; ni++)
                acc[mi][ni] = __builtin_amdgcn_mfma_f32_16x16x32_bf16(af[mi], bfr[ni], acc[mi][ni], 0, 0, 0);
    }

    #pragma unroll
    for (int mi = 0; mi < 2; mi++)
        #pragma unroll
        for (int ni = 0; ni < 4; ni++) {
            const int gr = r0 + wave * 32 + mi * 16 + quad * 4;
            const int gc = n0 + ni * 16 + col;
            const float bb = bias[gc];
            #pragma unroll
            for (int r = 0; r < 4; r++)
                C[(size_t)(gr + r) * D_MODEL + gc] = acc[mi][ni][r] + bb;
        }
}

// ---------------------------------------------------------------------------
extern "C" void kernel_launch(void* const* d_in, const int* in_sizes, int n_in,
                              void* d_out, int out_size, void* d_ws, size_t ws_size,
                              hipStream_t stream) {
    (void)in_sizes; (void)n_in; (void)out_size; (void)ws_size;
    const float* query = (const float*)d_in[0];
    const float* key_  = (const float*)d_in[1];
    const float* value = (const float*)d_in[2];
    const int*   mask  = (const int*)d_in[3];
    const float* wq = (const float*)d_in[4];  const float* bq = (const float*)d_in[5];
    const float* wk = (const float*)d_in[6];  const float* bk = (const float*)d_in[7];
    const float* wv = (const float*)d_in[8];  const float* bv = (const float*)d_in[9];
    const float* wo = (const float*)d_in[10]; const float* bo = (const float*)d_in[11];
    const float* spatial_w = (const float*)d_in[12]; const float* spatial_b = (const float*)d_in[13];
    const float* qproj_w   = (const float*)d_in[14]; const float* qproj_b   = (const float*)d_in[15];
    const float* kproj_w   = (const float*)d_in[16]; const float* kproj_b   = (const float*)d_in[17];
    const float* vlin_w    = (const float*)d_in[18]; const float* vlin_b    = (const float*)d_in[19];
    const float* chan_w    = (const float*)d_in[20]; const float* chan_b    = (const float*)d_in[21];
    float* out = (float*)d_out;

    char* ws = (char*)d_ws;
    u16* Qh  = (u16*)ws;                          // 8 MB [B,S,H,DK] bf16 (pre-scaled 1/8)
    u16* K2  = (u16*)(ws + ((size_t)8  << 20));   // 8 MB [B,S,H,DK] bf16
    u16* Xb  = (u16*)(ws + ((size_t)16 << 20));   // 8 MB [B,S,D] bf16 (attn out)
    u16* WT  = (u16*)(ws + ((size_t)24 << 20));   // 8 MB: 4 transposed weights
    u16* V2t = (u16*)(ws + ((size_t)32 << 20));   // 8 MB [B,H,DK,S] bf16
    float* mB = (float*)(ws + ((size_t)40 << 20));
    float* uB = mB + (size_t)BATCH * NH * S_LEN;
    float* vB = uB + (size_t)BATCH * NH * S_LEN;
    unsigned long long* Mbits = (unsigned long long*)(ws + ((size_t)41 << 20)); // 512 KB
    u16* Xbf = (u16*)(ws + ((size_t)42 << 20));   // 24 MB: 3x [B,S,D] bf16 inputs
    const size_t WSZ = (size_t)D_MODEL * D_MODEL;
    const size_t XSZ = (size_t)MROWS * D_MODEL;

    prep<<<dim3(9216), 256, 0, stream>>>(wq, wk, wv, wo, WT,
        query, key_, value, Xbf, mask, Mbits);
    proj_fused<<<dim3(32, 16, 3), 256, 0, stream>>>(Xbf, Xbf + XSZ, Xbf + 2 * XSZ,
        WT, WT + WSZ, WT + 2 * WSZ, bq, bk, bv,
        spatial_w, spatial_b, qproj_w, qproj_b, kproj_w, kproj_b,
        vlin_w, vlin_b, chan_w, chan_b,
        Qh, K2, V2t, mB, uB, vB);
    attn_mfma<<<dim3(512), 256, 0, stream>>>(Qh, K2, V2t, mB, uB, vB, Mbits, Xb);
    out_gemm<<<dim3(32, 16), 256, 0, stream>>>(Xb, WT + 3 * WSZ, bo, out);
}

// Round 11
// 272.775 us; speedup vs baseline: 1.0329x; 1.0116x over previous
//
#include <hip/hip_runtime.h>
#include <math.h>

#define D_MODEL 1024
#define NH 16
#define DK 64
#define S_LEN 1024
#define BATCH 4
#define MROWS (BATCH * S_LEN)  // 4096

typedef short bf16x8 __attribute__((ext_vector_type(8)));
typedef float f32x4 __attribute__((ext_vector_type(4)));
typedef unsigned short u16;

__device__ __forceinline__ float elu1(float x) {
    return x > 0.f ? x : (expf(x) - 1.f);
}

__device__ __forceinline__ u16 f2bf(float f) {
    union { float f; unsigned u; } v; v.f = f;
    unsigned u = v.u;
    return (u16)((u + 0x7fffu + ((u >> 16) & 1u)) >> 16);
}

// round-to-nearest (ties up) bf16 cast: 2 VALU ops instead of 4.
__device__ __forceinline__ u16 f2bf_fast(float f) {
    union { float f; unsigned u; } v; v.f = f;
    return (u16)((v.u + 0x8000u) >> 16);
}

__device__ __forceinline__ void async16(const void* g, void* l) {
    __builtin_amdgcn_global_load_lds(
        (const __attribute__((address_space(1))) unsigned int*)g,
        (__attribute__((address_space(3))) unsigned int*)l,
        16, 0, 0);
}

// ---------------------------------------------------------------------------
// prep: fused cast_wt + cast_x + mask_pack (all independent, all memory-bound)
// in ONE dispatch. Blocks 0..1023: weight transpose-cast; 1024..7167: X cast;
// 7168..9215: mask bitpack. Branches are block-uniform.
__global__ __launch_bounds__(256) void prep(
    const float* __restrict__ wq, const float* __restrict__ wk,
    const float* __restrict__ wv, const float* __restrict__ wo,
    u16* __restrict__ WT,
    const float* __restrict__ Xq, const float* __restrict__ Xk,
    const float* __restrict__ Xv, u16* __restrict__ Xb,
    const int* __restrict__ mask, unsigned long long* __restrict__ Mb)
{
    __shared__ float T[64][65];
    const int bid = blockIdx.x;
    const int tid = threadIdx.x;

    if (bid < 1024) {
        // ---- cast_wt: W f32 [k][n] -> WT bf16 [n][k] ----
        const int z = bid >> 8;
        const int rem = bid & 255;
        const int n0 = (rem & 15) * 64, k0 = (rem >> 4) * 64;
        const float* W = (z == 0) ? wq : ((z == 1) ? wk : ((z == 2) ? wv : wo));
        u16* O = WT + (size_t)z * D_MODEL * D_MODEL;
        const int r = tid >> 4, c4 = (tid & 15) * 4;
        #pragma unroll
        for (int p = 0; p < 4; p++) {
            float4 v = *(const float4*)&W[(size_t)(k0 + r + p * 16) * D_MODEL + n0 + c4];
            T[r + p * 16][c4 + 0] = v.x; T[r + p * 16][c4 + 1] = v.y;
            T[r + p * 16][c4 + 2] = v.z; T[r + p * 16][c4 + 3] = v.w;
        }
        __syncthreads();
        #pragma unroll
        for (int p = 0; p < 4; p++) {
            const int i = r + p * 16;
            ushort4 o4;
            o4.x = f2bf(T[c4 + 0][i]); o4.y = f2bf(T[c4 + 1][i]);
            o4.z = f2bf(T[c4 + 2][i]); o4.w = f2bf(T[c4 + 3][i]);
            *(ushort4*)&O[(size_t)(n0 + i) * D_MODEL + k0 + c4] = o4;
        }
    } else if (bid < 1024 + 6144) {
        // ---- cast_x: X f32 -> bf16 ----
        const int idx = bid - 1024;
        const int z = idx >> 11;            // 0..2
        const int bx = idx & 2047;
        const float* X = (z == 0) ? Xq : ((z == 1) ? Xk : Xv);
        u16* O = Xb + (size_t)z * MROWS * D_MODEL;
        const size_t i = ((size_t)bx * 256 + tid) * 8;
        float4 a = *(const float4*)&X[i];
        float4 b = *(const float4*)&X[i + 4];
        ushort4 o0, o1;
        o0.x = f2bf(a.x); o0.y = f2bf(a.y); o0.z = f2bf(a.z); o0.w = f2bf(a.w);
        o1.x = f2bf(b.x); o1.y = f2bf(b.y); o1.z = f2bf(b.z); o1.w = f2bf(b.w);
        *(ushort4*)&O[i] = o0;
        *(ushort4*)&O[i + 4] = o1;
    } else {
        // ---- mask_pack: int32 [B][S][S] -> u64 bitmask via ballot ----
        const int bx = bid - 7168;
        const int gw = (bx * 256 + tid) >> 6;   // 0..8191
        const int lane = tid & 63;
        int v[8];
        #pragma unroll
        for (int i = 0; i < 8; i++)
            v[i] = mask[((size_t)gw + (size_t)i * 8192) * 64 + lane];
        #pragma unroll
        for (int i = 0; i < 8; i++) {
            unsigned long long bits = __ballot(v[i] != 0);
            if (lane == 0) Mb[(size_t)gw + (size_t)i * 8192] = bits;
        }
    }
}

// ---------------------------------------------------------------------------
// proj_fused v7: 128x64 tile, one head per block, BK=32, DOUBLE-BUFFERED
// LDS with ONE barrier per K-step (T3 minimum-2-phase): stage tile t+1 into
// buf^1 BEFORE computing buf[cur], so the vmcnt(0) drain at the barrier
// happens AFTER the MFMA cluster (load latency hidden under compute).
// LDS: 2 x (As[128][32]+Bs[64][32]) = 24 KB + W2t 9 KB = 33.8 KB (same as
// v6 -> occupancy unchanged). Swizzle: v4's 64B-row XOR.
__global__ __launch_bounds__(256) void proj_fused(
    const u16* __restrict__ Xq, const u16* __restrict__ Xk, const u16* __restrict__ Xv,
    const u16* __restrict__ WTq, const u16* __restrict__ WTk, const u16* __restrict__ WTv,
    const float* __restrict__ bq, const float* __restrict__ bk, const float* __restrict__ bv,
    const float* __restrict__ spatial_w, const float* __restrict__ spatial_b,
    const float* __restrict__ qproj_w, const float* __restrict__ qproj_b,
    const float* __restrict__ kproj_w, const float* __restrict__ kproj_b,
    const float* __restrict__ vlin_w, const float* __restrict__ vlin_b,
    const float* __restrict__ chan_w, const float* __restrict__ chan_b,
    u16* __restrict__ Qh, u16* __restrict__ K2, u16* __restrict__ V2t,
    float* __restrict__ mB, float* __restrict__ uB, float* __restrict__ vB)
{
    // u16 units: buf p at p*6144: As [128][32] (4096) + Bs [64][32] (2048).
    // W2t [64][72] = 12288..16895. Phase 2: Pchunk = smem + wave*1536
    // (dead buf0 area); Tb (V transpose) aliases W2t.
    __shared__ __align__(16) u16 smem[16896];
    __shared__ float auxA[64];
    __shared__ float auxS;

    u16* W2t = smem + 12288;

    const int z = blockIdx.z;
    const u16* X = (z == 0) ? Xq : ((z == 1) ? Xk : Xv);
    const u16* WT = (z == 0) ? WTq : ((z == 1) ? WTk : WTv);
    const float* B1 = (z == 0) ? bq : ((z == 1) ? bk : bv);
    const float* W2 = (z == 0) ? spatial_w : ((z == 1) ? kproj_w : vlin_w);
    const float* B2 = (z == 0) ? spatial_b : ((z == 1) ? kproj_b : vlin_b);

    const int tid = threadIdx.x;
    const int wave = tid >> 6, lane = tid & 63;
    const int col = lane & 15, quad = lane >> 4;
    const int r0 = blockIdx.x * 128;
    const int hh = blockIdx.y;          // head (one per block)
    const int n0 = hh * 64;

    // ---- stage W2t (transposed bf16) + aux ----
    #pragma unroll
    for (int p = 0; p < 4; p++) {
        int idx = p * 256 + tid;
        int f = idx >> 4, e4 = (idx & 15) * 4;
        float4 w4 = *(const float4*)&W2[f * 64 + e4];
        W2t[(e4 + 0) * 72 + f] = f2bf(w4.x);
        W2t[(e4 + 1) * 72 + f] = f2bf(w4.y);
        W2t[(e4 + 2) * 72 + f] = f2bf(w4.z);
        W2t[(e4 + 3) * 72 + f] = f2bf(w4.w);
    }
    if (z == 0) {
        {
            int row = tid >> 2, part = tid & 3;
            float s = 0.f;
            for (int e = part * 16; e < part * 16 + 16; e++) s += qproj_w[row * 64 + e];
            s += __shfl_xor(s, 1);
            s += __shfl_xor(s, 2);
            if (part == 0) auxA[row] = s * (1.f / 64.f);
        }
        if (tid < 64) {
            float s = qproj_b[tid];
            #pragma unroll
            for (int m = 1; m < 64; m <<= 1) s += __shfl_xor(s, m);
            if (tid == 0) auxS = s * (1.f / 64.f);
        }
    }

    // ---- phase 1: GEMM 128x64, BK=32, dbuf + 1 barrier/step ----
    const int srow = lane >> 2;                          // 0..15
    const int sg = ((lane & 3) ^ ((lane >> 3) & 3)) * 8; // swizzled src granule

    const u16* ap = X + (size_t)(r0 + wave * 32 + srow) * D_MODEL + sg;
    const u16* bp = WT + (size_t)(n0 + wave * 16 + srow) * D_MODEL + sg;

    f32x4 acc[2][4];
    #pragma unroll
    for (int i = 0; i < 2; i++)
        #pragma unroll
        for (int j = 0; j < 4; j++)
            acc[i][j] = (f32x4){0.f, 0.f, 0.f, 0.f};

    const int gsw = (quad ^ ((col >> 1) & 3)) * 8;       // swizzled read granule

#define PF_STAGE(P, K)                                                        \
    do {                                                                      \
        u16* a0_ = smem + (P) * 6144 + wave * 1024;                           \
        u16* b0_ = smem + (P) * 6144 + 4096 + wave * 512;                     \
        async16(ap + (K), a0_);                                               \
        async16(ap + (size_t)16 * D_MODEL + (K), a0_ + 512);                  \
        async16(bp + (K), b0_);                                               \
    } while (0)

#define PF_COMPUTE(P)                                                         \
    do {                                                                      \
        const u16* Ab_ = smem + (P) * 6144 + (wave * 32 + col) * 32 + gsw;    \
        const u16* Bb_ = smem + (P) * 6144 + 4096 + col * 32 + gsw;           \
        bf16x8 af_[2], bf_[4];                                                \
        _Pragma("unroll")                                                     \
        for (int mi = 0; mi < 2; mi++) af_[mi] = *(const bf16x8*)(Ab_ + mi * 512); \
        _Pragma("unroll")                                                     \
        for (int ni = 0; ni < 4; ni++) bf_[ni] = *(const bf16x8*)(Bb_ + ni * 512); \
        _Pragma("unroll")                                                     \
        for (int mi = 0; mi < 2; mi++)                                        \
            _Pragma("unroll")                                                 \
            for (int ni = 0; ni < 4; ni++)                                    \
                acc[mi][ni] = __builtin_amdgcn_mfma_f32_16x16x32_bf16(        \
                    af_[mi], bf_[ni], acc[mi][ni], 0, 0, 0);                  \
    } while (0)

    PF_STAGE(0, 0);
    __syncthreads();
    for (int k0 = 0; k0 < D_MODEL; k0 += 64) {
        // step A: compute buf0 (tile k0), stage k0+32 into buf1
        if (k0 + 32 < D_MODEL) PF_STAGE(1, k0 + 32);
        PF_COMPUTE(0);
        __syncthreads();   // drains vmcnt (buf1 stores) + publishes
        // step B: compute buf1 (tile k0+32), stage k0+64 into buf0
        if (k0 + 64 < D_MODEL) PF_STAGE(0, k0 + 64);
        PF_COMPUTE(1);
        __syncthreads();
    }
#undef PF_STAGE
#undef PF_COMPUTE

    // ---- phase 2: epilogue ----
    float b1v[4];
    #pragma unroll
    for (int ni = 0; ni < 4; ni++) b1v[ni] = B1[n0 + ni * 16 + col];

    const int rbase = r0 + wave * 32;
    const int b = r0 >> 10;
    const int s0 = (r0 & 1023) + wave * 32;
    const size_t svecbase = ((size_t)b * NH + hh) * S_LEN;

    if (z == 1) {
        float cw[4], cb[4];
        #pragma unroll
        for (int ni = 0; ni < 4; ni++) { cw[ni] = chan_w[ni * 16 + col]; cb[ni] = chan_b[ni * 16 + col]; }
        #pragma unroll
        for (int mi = 0; mi < 2; mi++)
            #pragma unroll
            for (int r = 0; r < 4; r++) {
                float su = 0.f, sv = 0.f;
                #pragma unroll
                for (int ni = 0; ni < 4; ni++) {
                    float p = acc[mi][ni][r] + b1v[ni];
                    su += p * cw[ni];
                    sv += p * cb[ni];
                }
                su += __shfl_xor(su, 1); su += __shfl_xor(su, 2);
                su += __shfl_xor(su, 4); su += __shfl_xor(su, 8);
                sv += __shfl_xor(sv, 1); sv += __shfl_xor(sv, 2);
                sv += __shfl_xor(sv, 4); sv += __shfl_xor(sv, 8);
                if (col == 0) {
                    const size_t idx = svecbase + s0 + mi * 16 + quad * 4 + r;
                    uB[idx] = su;
                    vB[idx] = sv;
                }
            }
    }

    __syncthreads();  // phase-1 buf reads done; safe to alias Pchunk

    u16* Pchunk = smem + wave * 1536;
    bf16x8 bf2r[4][2];
    #pragma unroll
    for (int ni = 0; ni < 4; ni++) {
        bf2r[ni][0] = *(const bf16x8*)&W2t[(ni * 16 + col) * 72 + quad * 8];
        bf2r[ni][1] = *(const bf16x8*)&W2t[(ni * 16 + col) * 72 + 32 + quad * 8];
    }
    float qs[2][4][4];
    #pragma unroll
    for (int mi = 0; mi < 2; mi++) {
        #pragma unroll
        for (int ni = 0; ni < 4; ni++)
            #pragma unroll
            for (int r = 0; r < 4; r++)
                Pchunk[(quad * 4 + r) * 72 + ni * 16 + col] = f2bf(acc[mi][ni][r] + b1v[ni]);
        __builtin_amdgcn_s_waitcnt(0xc07f);  // lgkmcnt(0): wave-local chunk visible
        __builtin_amdgcn_sched_barrier(0);
        bf16x8 a0 = *(const bf16x8*)&Pchunk[col * 72 + quad * 8];
        bf16x8 a1 = *(const bf16x8*)&Pchunk[col * 72 + 32 + quad * 8];
        __builtin_amdgcn_s_waitcnt(0xc07f);  // reads done before mi+1 overwrites
        __builtin_amdgcn_sched_barrier(0);
        #pragma unroll
        for (int ni = 0; ni < 4; ni++) {
            f32x4 c = (f32x4){0.f, 0.f, 0.f, 0.f};
            c = __builtin_amdgcn_mfma_f32_16x16x32_bf16(a0, bf2r[ni][0], c, 0, 0, 0);
            c = __builtin_amdgcn_mfma_f32_16x16x32_bf16(a1, bf2r[ni][1], c, 0, 0, 0);
            const float bb = B2[ni * 16 + col];
            #pragma unroll
            for (int r = 0; r < 4; r++) qs[mi][ni][r] = elu1(c[r] + bb);
        }
    }

    if (z == 0) {
        float aw[4];
        #pragma unroll
        for (int ni = 0; ni < 4; ni++) aw[ni] = auxA[ni * 16 + col];
        #pragma unroll
        for (int mi = 0; mi < 2; mi++)
            #pragma unroll
            for (int r = 0; r < 4; r++) {
                float pm = 0.f;
                #pragma unroll
                for (int ni = 0; ni < 4; ni++) pm += qs[mi][ni][r] * aw[ni];
                pm += __shfl_xor(pm, 1); pm += __shfl_xor(pm, 2);
                pm += __shfl_xor(pm, 4); pm += __shfl_xor(pm, 8);
                if (col == 0)
                    mB[svecbase + s0 + mi * 16 + quad * 4 + r] = pm + auxS;
            }
        #pragma unroll
        for (int mi = 0; mi < 2; mi++)
            #pragma unroll
            for (int ni = 0; ni < 4; ni++)
                #pragma unroll
                for (int r = 0; r < 4; r++)
                    Qh[(size_t)(rbase + mi * 16 + quad * 4 + r) * D_MODEL
                       + n0 + ni * 16 + col] = f2bf(qs[mi][ni][r] * 0.125f);
    } else if (z == 1) {
        #pragma unroll
        for (int mi = 0; mi < 2; mi++)
            #pragma unroll
            for (int ni = 0; ni < 4; ni++)
                #pragma unroll
                for (int r = 0; r < 4; r++)
                    K2[(size_t)(rbase + mi * 16 + quad * 4 + r) * D_MODEL
                       + n0 + ni * 16 + col] = f2bf(qs[mi][ni][r]);
    } else {
        u16* Tb = W2t;
        __syncthreads();
        #pragma unroll
        for (int p = 0; p < 2; p++) {
            if ((wave >> 1) == p) {
                const int sloc = (wave & 1) * 32;
                #pragma unroll
                for (int mi = 0; mi < 2; mi++)
                    #pragma unroll
                    for (int ni = 0; ni < 4; ni++)
                        #pragma unroll
                        for (int r = 0; r < 4; r++)
                            Tb[(ni * 16 + col) * 72 + sloc + mi * 16 + quad * 4 + r] =
                                f2bf(qs[mi][ni][r]);
            }
            __syncthreads();
            {
                const int d = tid >> 2, seg = tid & 3;
                u16* dst = V2t + (((size_t)b * NH + hh) * DK + d) * S_LEN
                         + (r0 & 1023) + p * 64 + seg * 16;
                *(uint4*)dst = *(const uint4*)&Tb[d * 72 + seg * 16];
                *(uint4*)(dst + 8) = *(const uint4*)&Tb[d * 72 + seg * 16 + 8];
            }
            if (p == 0) __syncthreads();
        }
    }
}

// ---------------------------------------------------------------------------
// MFMA flash attention v4: QBLK=128 (two 64-row Q chunks per block, 512
// blocks). K/V staging, barriers, and K/V global reads halved per unit
// work vs v3. Gate params loaded per-tile (L2-resident) to keep VGPR < 128.
__global__ __launch_bounds__(256) void attn_mfma(
    const u16* __restrict__ Qh, const u16* __restrict__ K2h, const u16* __restrict__ V2t,
    const float* __restrict__ Mq, const float* __restrict__ Uk, const float* __restrict__ Vk,
    const unsigned long long* __restrict__ Mb, u16* __restrict__ X)
{
    __shared__ u16 K2s[64][72];
    __shared__ u16 V2s[64][72];
    __shared__ u16 Ps[4][16][72];

    const int tid = threadIdx.x;
    const int wave = tid >> 6, lane = tid & 63;
    const int col = lane & 15, quad = lane >> 4;

    // XCD swizzle: 512 blocks = 8 XCDs x 64. Each XCD gets 64 consecutive
    // o's = 8 q-tiles x 8 heads (2 MB K/V in its L2).
    const int f = blockIdx.x;
    const int o = (f & 7) * 64 + (f >> 3);
    const int q0 = (o & 7) * 128;
    const int h = (o >> 3) & 15;
    const int b = o >> 7;

    const size_t hb = ((size_t)(b * NH + h)) * S_LEN * DK;
    const size_t sb = ((size_t)(b * NH + h)) * S_LEN;

    bf16x8 qf0[2], qf1[2];
    float mqv[2][4];
    #pragma unroll
    for (int qc = 0; qc < 2; qc++) {
        const u16* qp = Qh + (size_t)(b * S_LEN + q0 + qc * 64 + wave * 16 + col) * D_MODEL
                      + h * 64 + quad * 8;
        qf0[qc] = *(const bf16x8*)qp;
        qf1[qc] = *(const bf16x8*)(qp + 32);
        #pragma unroll
        for (int r = 0; r < 4; r++)
            mqv[qc][r] = Mq[sb + q0 + qc * 64 + wave * 16 + quad * 4 + r];
    }

    const int srow = tid >> 2, sseg = tid & 3;
    const u16* ksrc = K2h + (size_t)(b * S_LEN + srow) * D_MODEL + h * 64 + sseg * 16;
    const u16* vsrc = V2t + hb + (size_t)srow * S_LEN + sseg * 16;
    const unsigned long long* mb0 = Mb
        + ((size_t)b * S_LEN + q0 + wave * 16 + quad * 4) * (S_LEN / 64);
    const unsigned msel0 = 1u << col, msel1 = msel0 << 16;

    // tile-0 prefetch (K/V only; gate params loaded per-tile, L2-resident)
    uint4 ka = *(const uint4*)(ksrc);
    uint4 kb = *(const uint4*)(ksrc + 8);
    uint4 va = *(const uint4*)(vsrc);
    uint4 vb = *(const uint4*)(vsrc + 8);

    float psum[2][4];
    f32x4 o4[2][4];
    #pragma unroll
    for (int qc = 0; qc < 2; qc++) {
        #pragma unroll
        for (int r = 0; r < 4; r++) psum[qc][r] = 0.f;
        #pragma unroll
        for (int nb = 0; nb < 4; nb++) o4[qc][nb] = (f32x4){0.f, 0.f, 0.f, 0.f};
    }

    for (int t = 0; t < 16; t++) {
        *(uint4*)&K2s[srow][sseg * 16]     = ka;
        *(uint4*)&K2s[srow][sseg * 16 + 8] = kb;
        *(uint4*)&V2s[srow][sseg * 16]     = va;
        *(uint4*)&V2s[srow][sseg * 16 + 8] = vb;

        // gate params for this tile (L2-resident; latency hides under barrier)
        float ku[4], kv[4];
        #pragma unroll
        for (int nb = 0; nb < 4; nb++) {
            ku[nb] = Uk[sb + t * 64 + nb * 16 + col];
            kv[nb] = Vk[sb + t * 64 + nb * 16 + col];
        }
        __syncthreads();  // barrier A: stores visible

        if (t < 15) {   // reload K/V regs for t+1 (latency hidden under compute)
            const int k1 = (t + 1) * 64;
            const u16* ks = ksrc + (size_t)k1 * D_MODEL;
            const u16* vs = vsrc + k1;
            ka = *(const uint4*)(ks);
            kb = *(const uint4*)(ks + 8);
            va = *(const uint4*)(vs);
            vb = *(const uint4*)(vs + 8);
        }

        #pragma unroll
        for (int qc = 0; qc < 2; qc++) {
            // mask bits for this (q-chunk, tile)
            unsigned long long wm[4];
            #pragma unroll
            for (int r = 0; r < 4; r++)
                wm[r] = mb0[((size_t)qc * 64 + r) * 16 + t];

            // ---- QK^T (Q pre-scaled by 1/8) ----
            __builtin_amdgcn_s_setprio(1);
            f32x4 sc[4];
            #pragma unroll
            for (int nb = 0; nb < 4; nb++) {
                bf16x8 b0 = *(const bf16x8*)&K2s[nb * 16 + col][quad * 8];
                bf16x8 b1 = *(const bf16x8*)&K2s[nb * 16 + col][32 + quad * 8];
                f32x4 c = (f32x4){0.f, 0.f, 0.f, 0.f};
                c = __builtin_amdgcn_mfma_f32_16x16x32_bf16(qf0[qc], b0, c, 0, 0, 0);
                c = __builtin_amdgcn_mfma_f32_16x16x32_bf16(qf1[qc], b1, c, 0, 0, 0);
                sc[nb] = c;
            }
            __builtin_amdgcn_s_setprio(0);

            // ---- gate, mask (bit test), exp (fixed max 0) ----
            #pragma unroll
            for (int nb = 0; nb < 4; nb++) {
                #pragma unroll
                for (int r = 0; r < 4; r++) {
                    float e = __expf(-(mqv[qc][r] * ku[nb] + kv[nb]));
                    float g = __builtin_amdgcn_rcpf(1.f + e);
                    float sv = sc[nb][r] * g;
                    const unsigned bits = (nb < 2) ? (unsigned)wm[r]
                                                   : (unsigned)(wm[r] >> 32);
                    sv = (bits & ((nb & 1) ? msel1 : msel0)) ? sv : -30.f;
                    float p = __expf(sv);
                    psum[qc][r] += p;
                    Ps[wave][quad * 4 + r][nb * 16 + col] = f2bf_fast(p);
                }
            }
            __builtin_amdgcn_s_waitcnt(0xc07f);  // lgkmcnt(0): Ps writes visible
            __builtin_amdgcn_sched_barrier(0);
            bf16x8 a0 = *(const bf16x8*)&Ps[wave][col][quad * 8];
            bf16x8 a1 = *(const bf16x8*)&Ps[wave][col][32 + quad * 8];
            __builtin_amdgcn_s_waitcnt(0xc07f);  // reads done before qc+1 overwrites
            __builtin_amdgcn_sched_barrier(0);

            // ---- PV ----
            __builtin_amdgcn_s_setprio(1);
            #pragma unroll
            for (int nb = 0; nb < 4; nb++) {
                bf16x8 b0 = *(const bf16x8*)&V2s[nb * 16 + col][quad * 8];
                bf16x8 b1 = *(const bf16x8*)&V2s[nb * 16 + col][32 + quad * 8];
                o4[qc][nb] = __builtin_amdgcn_mfma_f32_16x16x32_bf16(a0, b0, o4[qc][nb], 0, 0, 0);
                o4[qc][nb] = __builtin_amdgcn_mfma_f32_16x16x32_bf16(a1, b1, o4[qc][nb], 0, 0, 0);
            }
            __builtin_amdgcn_s_setprio(0);
        }
        __syncthreads();  // barrier B: all reads done; next stores safe
    }

    #pragma unroll
    for (int qc = 0; qc < 2; qc++)
        #pragma unroll
        for (int r = 0; r < 4; r++) {
            float t = psum[qc][r];
            t += __shfl_xor(t, 1);
            t += __shfl_xor(t, 2);
            t += __shfl_xor(t, 4);
            t += __shfl_xor(t, 8);
            float inv = __builtin_amdgcn_rcpf(t);
            u16* xp = X + (size_t)(b * S_LEN + q0 + qc * 64 + wave * 16 + quad * 4 + r) * D_MODEL
                    + h * 64 + col;
            #pragma unroll
            for (int nb = 0; nb < 4; nb++)
                xp[nb * 16] = f2bf_fast(o4[qc][nb][r] * inv);
        }
}

// ---------------------------------------------------------------------------
// out_gemm v3: same T3 minimum-2-phase dbuf as proj v7. 128x64 tiles,
// grid (32,16) = 512 blocks. LDS 2 x 12 KB = 24 KB.
__global__ __launch_bounds__(256) void out_gemm(
    const u16* __restrict__ A, const u16* __restrict__ WT,
    const float* __restrict__ bias, float* __restrict__ C)
{
    __shared__ __align__(16) u16 smem[12288];   // buf p at p*6144

    const int tid = threadIdx.x;
    const int wave = tid >> 6, lane = tid & 63;
    const int col = lane & 15, quad = lane >> 4;
    const int r0 = blockIdx.x * 128, n0 = blockIdx.y * 64;

    const int srow = lane >> 2;
    const int sg = ((lane & 3) ^ ((lane >> 3) & 3)) * 8;
    const u16* ap = A + (size_t)(r0 + wave * 32 + srow) * D_MODEL + sg;
    const u16* bp = WT + (size_t)(n0 + wave * 16 + srow) * D_MODEL + sg;

    f32x4 acc[2][4];
    #pragma unroll
    for (int i = 0; i < 2; i++)
        #pragma unroll
        for (int j = 0; j < 4; j++)
            acc[i][j] = (f32x4){0.f, 0.f, 0.f, 0.f};

    const int gsw = (quad ^ ((col >> 1) & 3)) * 8;

#define OG_STAGE(P, K)                                                        \
    do {                                                                      \
        u16* a0_ = smem + (P) * 6144 + wave * 1024;                           \
        u16* b0_ = smem + (P) * 6144 + 4096 + wave * 512;                     \
        async16(ap + (K), a0_);                                               \
        async16(ap + (size_t)16 * D_MODEL + (K), a0_ + 512);                  \
        async16(bp + (K), b0_);                                               \
    } while (0)

#define OG_COMPUTE(P)                                                         \
    do {                                                                      \
        const u16* Ab_ = smem + (P) * 6144 + (wave * 32 + col) * 32 + gsw;    \
        const u16* Bb_ = smem + (P) * 6144 + 4096 + col * 32 + gsw;           \
        bf16x8 af_[2], bf_[4];                                                \
        _Pragma("unroll")                                                     \
        for (int mi = 0; mi < 2; mi++) af_[mi] = *(const bf16x8*)(Ab_ + mi * 512); \
        _Pragma("unroll")                                                     \
        for (int ni = 0; ni < 4; ni++) bf_[ni] = *(const bf16x8*)(Bb_ + ni * 512); \
        _Pragma("unroll")                                                     \
        for (int mi = 0; mi < 2; mi++)                                        \
            _Pragma("unroll")                                                 \
            for (int ni = 0; ni < 4; ni++)                                    \
                acc[mi][ni] = __builtin_amdgcn_mfma_f32_16x16x32_bf16(        \
                    af_[mi], bf_[ni], acc[mi][ni], 0, 0, 0);                  \
    } while (0)

    OG_STAGE(0, 0);
    __syncthreads();
    for (int k0 = 0; k0 < D_MODEL; k0 += 64) {
        if (k0 + 32 < D_MODEL) OG_STAGE(1, k0 + 32);
        OG_COMPUTE(0);
        __syncthreads();
        if (k0 + 64 < D_MODEL) OG_STAGE(0, k0 + 64);
        OG_COMPUTE(1);
        __syncthreads();
    }
#undef OG_STAGE
#undef OG_COMPUTE

    #pragma unroll
    for (int mi = 0; mi < 2; mi++)
        #pragma unroll
        for (int ni = 0; ni < 4; ni++) {
            const int gr = r0 + wave * 32 + mi * 16 + quad * 4;
            const int gc = n0 + ni * 16 + col;
            const float bb = bias[gc];
            #pragma unroll
            for (int r = 0; r < 4; r++)
                C[(size_t)(gr + r) * D_MODEL + gc] = acc[mi][ni][r] + bb;
        }
}

// ---------------------------------------------------------------------------
extern "C" void kernel_launch(void* const* d_in, const int* in_sizes, int n_in,
                              void* d_out, int out_size, void* d_ws, size_t ws_size,
                              hipStream_t stream) {
    (void)in_sizes; (void)n_in; (void)out_size; (void)ws_size;
    const float* query = (const float*)d_in[0];
    const float* key_  = (const float*)d_in[1];
    const float* value = (const float*)d_in[2];
    const int*   mask  = (const int*)d_in[3];
    const float* wq = (const float*)d_in[4];  const float* bq = (const float*)d_in[5];
    const float* wk = (const float*)d_in[6];  const float* bk = (const float*)d_in[7];
    const float* wv = (const float*)d_in[8];  const float* bv = (const float*)d_in[9];
    const float* wo = (const float*)d_in[10]; const float* bo = (const float*)d_in[11];
    const float* spatial_w = (const float*)d_in[12]; const float* spatial_b = (const float*)d_in[13];
    const float* qproj_w   = (const float*)d_in[14]; const float* qproj_b   = (const float*)d_in[15];
    const float* kproj_w   = (const float*)d_in[16]; const float* kproj_b   = (const float*)d_in[17];
    const float* vlin_w    = (const float*)d_in[18]; const float* vlin_b    = (const float*)d_in[19];
    const float* chan_w    = (const float*)d_in[20]; const float* chan_b    = (const float*)d_in[21];
    float* out = (float*)d_out;

    char* ws = (char*)d_ws;
    u16* Qh  = (u16*)ws;                          // 8 MB [B,S,H,DK] bf16 (pre-scaled 1/8)
    u16* K2  = (u16*)(ws + ((size_t)8  << 20));   // 8 MB [B,S,H,DK] bf16
    u16* Xb  = (u16*)(ws + ((size_t)16 << 20));   // 8 MB [B,S,D] bf16 (attn out)
    u16* WT  = (u16*)(ws + ((size_t)24 << 20));   // 8 MB: 4 transposed weights
    u16* V2t = (u16*)(ws + ((size_t)32 << 20));   // 8 MB [B,H,DK,S] bf16
    float* mB = (float*)(ws + ((size_t)40 << 20));
    float* uB = mB + (size_t)BATCH * NH * S_LEN;
    float* vB = uB + (size_t)BATCH * NH * S_LEN;
    unsigned long long* Mbits = (unsigned long long*)(ws + ((size_t)41 << 20)); // 512 KB
    u16* Xbf = (u16*)(ws + ((size_t)42 << 20));   // 24 MB: 3x [B,S,D] bf16 inputs
    const size_t WSZ = (size_t)D_MODEL * D_MODEL;
    const size_t XSZ = (size_t)MROWS * D_MODEL;

    prep<<<dim3(9216), 256, 0, stream>>>(wq, wk, wv, wo, WT,
        query, key_, value, Xbf, mask, Mbits);
    proj_fused<<<dim3(32, 16, 3), 256, 0, stream>>>(Xbf, Xbf + XSZ, Xbf + 2 * XSZ,
        WT, WT + WSZ, WT + 2 * WSZ, bq, bk, bv,
        spatial_w, spatial_b, qproj_w, qproj_b, kproj_w, kproj_b,
        vlin_w, vlin_b, chan_w, chan_b,
        Qh, K2, V2t, mB, uB, vB);
    attn_mfma<<<dim3(512), 256, 0, stream>>>(Qh, K2, V2t, mB, uB, vB, Mbits, Xb);
    out_gemm<<<dim3(32, 16), 256, 0, stream>>>(Xb, WT + 3 * WSZ, bo, out);
}